// Round 1
// baseline (3338.696 us; speedup 1.0000x reference)
//
#include <hip/hip_runtime.h>
#include <hip/hip_bf16.h>
#include <math.h>

#define B_ 4
#define N_ 2048
#define D_ 1024
#define WIN_ 4
#define KTOP 8
#define ALPHA_ 0.3f
#define SCALE_ (1.0f/32.0f)

// ---------------------------------------------------------------------------
// Generic f32 GEMM: C[M x Nc] = X[M x K] @ W[K x Nc] + bias, row-major,
// C row stride = ldc. BM=BN=128, BK=16, 256 threads, 8x8 microtile.
// ---------------------------------------------------------------------------
__global__ __launch_bounds__(256)
void gemm_bias(const float* __restrict__ X, const float* __restrict__ W,
               const float* __restrict__ bias, float* __restrict__ C,
               int M, int K, int Nc, int ldc)
{
    __shared__ float As[16][128];   // transposed: As[k][m]
    __shared__ float Bs[16][128];   // Bs[k][n]
    const int tid = threadIdx.x;
    const int tx = tid & 15;
    const int ty = tid >> 4;
    const int m0 = blockIdx.y * 128;
    const int n0 = blockIdx.x * 128;

    float acc[8][8];
#pragma unroll
    for (int i = 0; i < 8; ++i)
#pragma unroll
        for (int j = 0; j < 8; ++j) acc[i][j] = 0.f;

    for (int k0 = 0; k0 < K; k0 += 16) {
        // A tile: 128 rows x 16 k = 512 float4, 2 per thread, store transposed
#pragma unroll
        for (int it = 0; it < 2; ++it) {
            int lin = tid + it * 256;
            int row = lin >> 2;
            int c4  = (lin & 3) << 2;
            float4 a = *reinterpret_cast<const float4*>(&X[(size_t)(m0 + row) * K + k0 + c4]);
            As[c4 + 0][row] = a.x; As[c4 + 1][row] = a.y;
            As[c4 + 2][row] = a.z; As[c4 + 3][row] = a.w;
        }
        // B tile: 16 k x 128 n = 512 float4, 2 per thread
#pragma unroll
        for (int it = 0; it < 2; ++it) {
            int lin = tid + it * 256;
            int kk = lin >> 5;
            int c4 = (lin & 31) << 2;
            *reinterpret_cast<float4*>(&Bs[kk][c4]) =
                *reinterpret_cast<const float4*>(&W[(size_t)(k0 + kk) * Nc + n0 + c4]);
        }
        __syncthreads();
#pragma unroll 4
        for (int kk = 0; kk < 16; ++kk) {
            float4 a0 = *reinterpret_cast<const float4*>(&As[kk][ty * 8]);
            float4 a1 = *reinterpret_cast<const float4*>(&As[kk][ty * 8 + 4]);
            float4 b0 = *reinterpret_cast<const float4*>(&Bs[kk][tx * 4]);
            float4 b1 = *reinterpret_cast<const float4*>(&Bs[kk][64 + tx * 4]);
            float av[8] = {a0.x,a0.y,a0.z,a0.w,a1.x,a1.y,a1.z,a1.w};
            float bv[8] = {b0.x,b0.y,b0.z,b0.w,b1.x,b1.y,b1.z,b1.w};
#pragma unroll
            for (int i = 0; i < 8; ++i)
#pragma unroll
                for (int j = 0; j < 8; ++j)
                    acc[i][j] = fmaf(av[i], bv[j], acc[i][j]);
        }
        __syncthreads();
    }
    float4 bb0 = make_float4(0.f,0.f,0.f,0.f), bb1 = make_float4(0.f,0.f,0.f,0.f);
    if (bias) {
        bb0 = *reinterpret_cast<const float4*>(&bias[n0 + tx * 4]);
        bb1 = *reinterpret_cast<const float4*>(&bias[n0 + 64 + tx * 4]);
    }
#pragma unroll
    for (int i = 0; i < 8; ++i) {
        size_t row = (size_t)(m0 + ty * 8 + i);
        float4 o0 = make_float4(acc[i][0]+bb0.x, acc[i][1]+bb0.y, acc[i][2]+bb0.z, acc[i][3]+bb0.w);
        float4 o1 = make_float4(acc[i][4]+bb1.x, acc[i][5]+bb1.y, acc[i][6]+bb1.z, acc[i][7]+bb1.w);
        *reinterpret_cast<float4*>(&C[row * ldc + n0 + tx * 4]) = o0;
        *reinterpret_cast<float4*>(&C[row * ldc + n0 + 64 + tx * 4]) = o1;
    }
}

// ---------------------------------------------------------------------------
// S[b,n,:] = mean_w silu(A[b,n,:] + Nb[b,n-w,:]) , Nb term 0 when n<w.
// A already contains mu@Wm1_top + bm1. In-place into A.
// ---------------------------------------------------------------------------
__global__ __launch_bounds__(256)
void silu_mean(float* __restrict__ A, const float* __restrict__ Nb)
{
    size_t idx4 = (size_t)blockIdx.x * blockDim.x + threadIdx.x; // one float4 each
    size_t base = idx4 << 2;
    int n = (int)((base >> 10) & (N_ - 1));   // D_=1024
    float4 a = *reinterpret_cast<const float4*>(&A[base]);
    float sx = 0.f, sy = 0.f, sz = 0.f, sw = 0.f;
#pragma unroll
    for (int w = 1; w <= WIN_; ++w) {
        float xx = a.x, xy = a.y, xz = a.z, xw = a.w;
        if (n >= w) {
            const float4 nb = *reinterpret_cast<const float4*>(&Nb[base - (size_t)w * D_]);
            xx += nb.x; xy += nb.y; xz += nb.z; xw += nb.w;
        }
        sx += xx / (1.f + __expf(-xx));
        sy += xy / (1.f + __expf(-xy));
        sz += xz / (1.f + __expf(-xz));
        sw += xw / (1.f + __expf(-xw));
    }
    float4 o = make_float4(sx * 0.25f, sy * 0.25f, sz * 0.25f, sw * 0.25f);
    *reinterpret_cast<float4*>(&A[base]) = o;
}

// ---------------------------------------------------------------------------
// Fused causal scores + top-8 + softmax + V-gather.
// Grid (64, B). Block 256. Each block handles row-groups g and 127-g (RT=16
// rows each) to balance the causal triangle. Score tile RT x MT in registers
// (4 per thread), per-thread top-8, final merge of 16 partial top-8s per row.
// Writes global_msgs into CC[:, D:2D] (row stride 2D).
// ---------------------------------------------------------------------------
#define RT 16
#define MT 64
#define KC 64

__global__ __launch_bounds__(256)
void attn_topk(const float* __restrict__ Q, const float* __restrict__ Km,
               const float* __restrict__ V, const float* __restrict__ pher,
               float* __restrict__ CC)
{
    __shared__ float Qs[KC][RT];
    __shared__ float Ks[KC][MT];
    __shared__ float Ps[MT];
    __shared__ float MV[RT][129];
    __shared__ int   MI[RT][129];
    __shared__ float Pp[RT][KTOP];
    __shared__ int   Pi[RT][KTOP];

    const int b  = blockIdx.y;
    const int g0 = blockIdx.x;            // 0..63
    const int tid = threadIdx.x;
    const int r = tid >> 4;               // 0..15 row within group
    const int c = tid & 15;               // 0..15 col group (4 cols each)

    for (int half = 0; half < 2; ++half) {
        const int grp = half ? (127 - g0) : g0;
        const int n0 = grp * RT;
        const int n  = n0 + r;            // causal limit for this thread's row

        float tv[KTOP]; int ti[KTOP];
#pragma unroll
        for (int j = 0; j < KTOP; ++j) { tv[j] = -INFINITY; ti[j] = 0; }

        const int mmax = n0 + RT - 1;
        const int ntiles = mmax / MT + 1;
        for (int mt = 0; mt < ntiles; ++mt) {
            const int m0 = mt * MT;
            if (tid < MT) Ps[tid] = pher[(size_t)b * N_ + m0 + tid];
            float acc0 = 0.f, acc1 = 0.f, acc2 = 0.f, acc3 = 0.f;
            for (int k0 = 0; k0 < D_; k0 += KC) {
                { // Q tile: 16 rows x 64 k = 256 float4, 1 per thread
                    int row = tid >> 4, c4 = (tid & 15) << 2;
                    float4 q = *reinterpret_cast<const float4*>(
                        &Q[((size_t)(b * N_ + n0 + row)) * D_ + k0 + c4]);
                    Qs[c4 + 0][row] = q.x; Qs[c4 + 1][row] = q.y;
                    Qs[c4 + 2][row] = q.z; Qs[c4 + 3][row] = q.w;
                }
#pragma unroll
                for (int it = 0; it < 4; ++it) { // K tile: 64 x 64 = 1024 f4
                    int lin = tid + it * 256;
                    int m = lin >> 4, c4 = (lin & 15) << 2;
                    float4 kv = *reinterpret_cast<const float4*>(
                        &Km[((size_t)(b * N_ + m0 + m)) * D_ + k0 + c4]);
                    Ks[c4 + 0][m] = kv.x; Ks[c4 + 1][m] = kv.y;
                    Ks[c4 + 2][m] = kv.z; Ks[c4 + 3][m] = kv.w;
                }
                __syncthreads();
#pragma unroll 8
                for (int kk = 0; kk < KC; ++kk) {
                    float q = Qs[kk][r];
                    float4 k4 = *reinterpret_cast<const float4*>(&Ks[kk][c * 4]);
                    acc0 = fmaf(q, k4.x, acc0);
                    acc1 = fmaf(q, k4.y, acc1);
                    acc2 = fmaf(q, k4.z, acc2);
                    acc3 = fmaf(q, k4.w, acc3);
                }
                __syncthreads();
            }
            // fold this tile's 4 scores into the per-thread top-8
            float accv[4] = {acc0, acc1, acc2, acc3};
#pragma unroll
            for (int j = 0; j < 4; ++j) {
                int m = m0 + c * 4 + j;
                if (m <= n) {
                    float s = accv[j] * SCALE_ + ALPHA_ * Ps[c * 4 + j];
                    if ((s > tv[KTOP-1]) || (s == tv[KTOP-1] && m < ti[KTOP-1])) {
                        float cs = s; int ci = m;
#pragma unroll
                        for (int q2 = 0; q2 < KTOP; ++q2) {
                            bool beats = (cs > tv[q2]) || (cs == tv[q2] && ci < ti[q2]);
                            if (beats) {
                                float t0 = tv[q2]; int t1 = ti[q2];
                                tv[q2] = cs; ti[q2] = ci; cs = t0; ci = t1;
                            }
                        }
                    }
                }
            }
            __syncthreads();   // protect Ps before next tile overwrites
        }
        // final merge: 16 partial top-8s per row
#pragma unroll
        for (int j = 0; j < KTOP; ++j) { MV[r][c * 8 + j] = tv[j]; MI[r][c * 8 + j] = ti[j]; }
        __syncthreads();
        if (tid < RT) {
            const int row = tid;
            float fv[KTOP]; int fi[KTOP];
#pragma unroll
            for (int j = 0; j < KTOP; ++j) { fv[j] = -INFINITY; fi[j] = 0x7fffffff; }
            for (int i = 0; i < 128; ++i) {
                float s = MV[row][i]; int m = MI[row][i];
                if (s == -INFINITY) continue;
                if ((s > fv[KTOP-1]) || (s == fv[KTOP-1] && m < fi[KTOP-1])) {
                    float cs = s; int ci = m;
#pragma unroll
                    for (int q2 = 0; q2 < KTOP; ++q2) {
                        bool beats = (cs > fv[q2]) || (cs == fv[q2] && ci < fi[q2]);
                        if (beats) {
                            float t0 = fv[q2]; int t1 = fi[q2];
                            fv[q2] = cs; fi[q2] = ci; cs = t0; ci = t1;
                        }
                    }
                }
            }
            float mx = fv[0];
            float e[KTOP]; float sum = 0.f;
#pragma unroll
            for (int j = 0; j < KTOP; ++j) {
                e[j] = (fv[j] == -INFINITY) ? 0.f : __expf(fv[j] - mx);
                sum += e[j];
            }
            float inv = 1.f / sum;
#pragma unroll
            for (int j = 0; j < KTOP; ++j) {
                Pp[row][j] = e[j] * inv;
                Pi[row][j] = (fv[j] == -INFINITY) ? 0 : fi[j];
            }
        }
        __syncthreads();
        // gather: each row is 256 float4; thread tid covers one float4/row
        for (int row = 0; row < RT; ++row) {
            float ox = 0.f, oy = 0.f, oz = 0.f, ow = 0.f;
#pragma unroll
            for (int j = 0; j < KTOP; ++j) {
                float p = Pp[row][j];
                const float4 v4 = *reinterpret_cast<const float4*>(
                    &V[((size_t)(b * N_ + Pi[row][j])) * D_ + tid * 4]);
                ox = fmaf(p, v4.x, ox); oy = fmaf(p, v4.y, oy);
                oz = fmaf(p, v4.z, oz); ow = fmaf(p, v4.w, ow);
            }
            float4 o = make_float4(ox, oy, oz, ow);
            *reinterpret_cast<float4*>(
                &CC[((size_t)(b * N_ + n0 + row)) * (2 * D_) + D_ + tid * 4]) = o;
        }
        __syncthreads();   // before next half reuses LDS
    }
}

// ---------------------------------------------------------------------------
extern "C" void kernel_launch(void* const* d_in, const int* in_sizes, int n_in,
                              void* d_out, int out_size, void* d_ws, size_t ws_size,
                              hipStream_t stream)
{
    const float* mu   = (const float*)d_in[0];
    const float* pher = (const float*)d_in[1];
    const float* Wq   = (const float*)d_in[2];
    const float* bq   = (const float*)d_in[3];
    const float* Wk   = (const float*)d_in[4];
    const float* bk   = (const float*)d_in[5];
    const float* Wv   = (const float*)d_in[6];
    const float* bv   = (const float*)d_in[7];
    const float* Wm1  = (const float*)d_in[8];
    const float* bm1  = (const float*)d_in[9];
    const float* Wm2  = (const float*)d_in[10];
    const float* bm2  = (const float*)d_in[11];
    const float* Wo   = (const float*)d_in[12];
    const float* bo   = (const float*)d_in[13];
    float* out = (float*)d_out;
    float* ws  = (float*)d_ws;

    const size_t SZ = (size_t)B_ * N_ * D_;     // 8388608
    const int M = B_ * N_;                      // 8192
    float* Qb = ws;
    float* Kb = ws + SZ;
    float* Vb = ws + 2 * SZ;
    float* Ab = ws + 3 * SZ;        // self pre-act (+bm1) -> becomes S in place
    float* Nb = ws + 4 * SZ;        // neighbor pre-act
    float* CC = ws + 4 * SZ;        // (M x 2D) concat buffer, overlaps dead Nb

    dim3 blk(256);
    dim3 gg(1024 / 128, M / 128);   // (8, 64)

    hipLaunchKernelGGL(gemm_bias, gg, blk, 0, stream, mu, Wq, bq, Qb, M, D_, D_, D_);
    hipLaunchKernelGGL(gemm_bias, gg, blk, 0, stream, mu, Wk, bk, Kb, M, D_, D_, D_);
    hipLaunchKernelGGL(gemm_bias, gg, blk, 0, stream, mu, Wv, bv, Vb, M, D_, D_, D_);
    hipLaunchKernelGGL(gemm_bias, gg, blk, 0, stream, mu, Wm1,            bm1,     Ab, M, D_, D_, D_);
    hipLaunchKernelGGL(gemm_bias, gg, blk, 0, stream, mu, Wm1 + (size_t)D_ * D_, (const float*)nullptr, Nb, M, D_, D_, D_);

    hipLaunchKernelGGL(silu_mean, dim3(SZ / 4 / 256), blk, 0, stream, Ab, Nb);

    // local msgs -> CC[:, 0:D]
    hipLaunchKernelGGL(gemm_bias, gg, blk, 0, stream, Ab, Wm2, bm2, CC, M, D_, D_, 2 * D_);

    // global msgs -> CC[:, D:2D]
    hipLaunchKernelGGL(attn_topk, dim3(64, B_), blk, 0, stream, Qb, Kb, Vb, pher, CC);

    // out = CC @ Wo + bo
    hipLaunchKernelGGL(gemm_bias, gg, blk, 0, stream, CC, Wo, bo, out, M, 2 * D_, D_, D_);

    (void)in_sizes; (void)n_in; (void)out_size; (void)ws_size;
}

// Round 3
// 2553.516 us; speedup vs baseline: 1.3075x; 1.3075x over previous
//
#include <hip/hip_runtime.h>
#include <hip/hip_bf16.h>
#include <math.h>

#define B_ 4
#define N_ 2048
#define D_ 1024
#define WIN_ 4
#define KTOP 8
#define ALPHA_ 0.3f
#define SCALE_ (1.0f/32.0f)
#define NCH 16          // N_/128 col chunks

// ---------------------------------------------------------------------------
// Generic f32 GEMM: C[M x Nc] = X[M x K] @ W[K x Nc] + bias, row-major,
// C row stride = ldc. BM=BN=128, BK=16, 256 threads, 8x8 microtile.
// ---------------------------------------------------------------------------
__global__ __launch_bounds__(256)
void gemm_bias(const float* __restrict__ X, const float* __restrict__ W,
               const float* __restrict__ bias, float* __restrict__ C,
               int M, int K, int Nc, int ldc)
{
    __shared__ float As[16][128];   // transposed: As[k][m]
    __shared__ float Bs[16][128];   // Bs[k][n]
    const int tid = threadIdx.x;
    const int tx = tid & 15;
    const int ty = tid >> 4;
    const int m0 = blockIdx.y * 128;
    const int n0 = blockIdx.x * 128;

    float acc[8][8];
#pragma unroll
    for (int i = 0; i < 8; ++i)
#pragma unroll
        for (int j = 0; j < 8; ++j) acc[i][j] = 0.f;

    for (int k0 = 0; k0 < K; k0 += 16) {
#pragma unroll
        for (int it = 0; it < 2; ++it) {
            int lin = tid + it * 256;
            int row = lin >> 2;
            int c4  = (lin & 3) << 2;
            float4 a = *reinterpret_cast<const float4*>(&X[(size_t)(m0 + row) * K + k0 + c4]);
            As[c4 + 0][row] = a.x; As[c4 + 1][row] = a.y;
            As[c4 + 2][row] = a.z; As[c4 + 3][row] = a.w;
        }
#pragma unroll
        for (int it = 0; it < 2; ++it) {
            int lin = tid + it * 256;
            int kk = lin >> 5;
            int c4 = (lin & 31) << 2;
            *reinterpret_cast<float4*>(&Bs[kk][c4]) =
                *reinterpret_cast<const float4*>(&W[(size_t)(k0 + kk) * Nc + n0 + c4]);
        }
        __syncthreads();
#pragma unroll 4
        for (int kk = 0; kk < 16; ++kk) {
            float4 a0 = *reinterpret_cast<const float4*>(&As[kk][ty * 8]);
            float4 a1 = *reinterpret_cast<const float4*>(&As[kk][ty * 8 + 4]);
            float4 b0 = *reinterpret_cast<const float4*>(&Bs[kk][tx * 4]);
            float4 b1 = *reinterpret_cast<const float4*>(&Bs[kk][64 + tx * 4]);
            float av[8] = {a0.x,a0.y,a0.z,a0.w,a1.x,a1.y,a1.z,a1.w};
            float bv[8] = {b0.x,b0.y,b0.z,b0.w,b1.x,b1.y,b1.z,b1.w};
#pragma unroll
            for (int i = 0; i < 8; ++i)
#pragma unroll
                for (int j = 0; j < 8; ++j)
                    acc[i][j] = fmaf(av[i], bv[j], acc[i][j]);
        }
        __syncthreads();
    }
    float4 bb0 = make_float4(0.f,0.f,0.f,0.f), bb1 = make_float4(0.f,0.f,0.f,0.f);
    if (bias) {
        bb0 = *reinterpret_cast<const float4*>(&bias[n0 + tx * 4]);
        bb1 = *reinterpret_cast<const float4*>(&bias[n0 + 64 + tx * 4]);
    }
#pragma unroll
    for (int i = 0; i < 8; ++i) {
        size_t row = (size_t)(m0 + ty * 8 + i);
        float4 o0 = make_float4(acc[i][0]+bb0.x, acc[i][1]+bb0.y, acc[i][2]+bb0.z, acc[i][3]+bb0.w);
        float4 o1 = make_float4(acc[i][4]+bb1.x, acc[i][5]+bb1.y, acc[i][6]+bb1.z, acc[i][7]+bb1.w);
        *reinterpret_cast<float4*>(&C[row * ldc + n0 + tx * 4]) = o0;
        *reinterpret_cast<float4*>(&C[row * ldc + n0 + 64 + tx * 4]) = o1;
    }
}

// ---------------------------------------------------------------------------
// S[b,n,:] = mean_w silu(A[b,n,:] + Nb[b,n-w,:]) , Nb term 0 when n<w.
// ---------------------------------------------------------------------------
__global__ __launch_bounds__(256)
void silu_mean(float* __restrict__ A, const float* __restrict__ Nb)
{
    size_t idx4 = (size_t)blockIdx.x * blockDim.x + threadIdx.x;
    size_t base = idx4 << 2;
    int n = (int)((base >> 10) & (N_ - 1));   // D_=1024
    float4 a = *reinterpret_cast<const float4*>(&A[base]);
    float sx = 0.f, sy = 0.f, sz = 0.f, sw = 0.f;
#pragma unroll
    for (int w = 1; w <= WIN_; ++w) {
        float xx = a.x, xy = a.y, xz = a.z, xw = a.w;
        if (n >= w) {
            const float4 nb = *reinterpret_cast<const float4*>(&Nb[base - (size_t)w * D_]);
            xx += nb.x; xy += nb.y; xz += nb.z; xw += nb.w;
        }
        sx += xx / (1.f + __expf(-xx));
        sy += xy / (1.f + __expf(-xy));
        sz += xz / (1.f + __expf(-xz));
        sw += xw / (1.f + __expf(-xw));
    }
    float4 o = make_float4(sx * 0.25f, sy * 0.25f, sz * 0.25f, sw * 0.25f);
    *reinterpret_cast<float4*>(&A[base]) = o;
}

// ---------------------------------------------------------------------------
// top-8 insertion, lexicographic (val desc, idx asc) == jax.lax.top_k order
// ---------------------------------------------------------------------------
__device__ inline void topk_insert(float (&tv)[KTOP], int (&ti)[KTOP], float s, int m)
{
    if ((s > tv[KTOP-1]) || (s == tv[KTOP-1] && m < ti[KTOP-1])) {
        float cs = s; int ci = m;
#pragma unroll
        for (int q = 0; q < KTOP; ++q) {
            bool beats = (cs > tv[q]) || (cs == tv[q] && ci < ti[q]);
            if (beats) { float t0 = tv[q]; int t1 = ti[q];
                         tv[q] = cs; ti[q] = ci; cs = t0; ci = t1; }
        }
    }
}

// ---------------------------------------------------------------------------
// attn_scores: per causal 128x128 tile, compute S = Q @ K^T * SCALE +
// ALPHA*pher + mask, reduce each row to top-8 over this chunk's 128 cols,
// write (val, idx) lists to workspace WV/WI [b][n][NCH][8].
// Grid: (136, B) -- exact enumeration of ch <= g pairs (g,ch in 0..15).
// Each (row, ch) slot has exactly ONE writer block -- no races.
// ---------------------------------------------------------------------------
__global__ __launch_bounds__(256)
void attn_scores(const float* __restrict__ Q, const float* __restrict__ Km,
                 const float* __restrict__ pher,
                 float* __restrict__ WV, int* __restrict__ WI)
{
    __shared__ char smem[32768];
    float* As = reinterpret_cast<float*>(smem);          // [16][128]
    float* Bs = As + 16 * 128;                           // [16][128]
    float* MV = reinterpret_cast<float*>(smem);          // [32][128] (reuse)
    int*   MI = reinterpret_cast<int*>(smem + 16384);    // [32][128]
    __shared__ float Ps[128];

    const int b = blockIdx.y;
    const int x = blockIdx.x;            // 0..135
    int g = 0;                           // largest g with g(g+1)/2 <= x
    while ((g + 1) * (g + 2) / 2 <= x) ++g;
    const int ch = x - g * (g + 1) / 2;  // col chunk, ch <= g
    const int n0 = g * 128;
    const int m0 = ch * 128;
    const int tid = threadIdx.x;
    const int tx = tid & 15;
    const int ty = tid >> 4;
    const size_t bN = (size_t)b * N_;

    if (tid < 128) Ps[tid] = pher[bN + m0 + tid];

    float acc[8][8];
#pragma unroll
    for (int i = 0; i < 8; ++i)
#pragma unroll
        for (int j = 0; j < 8; ++j) acc[i][j] = 0.f;

    for (int k0 = 0; k0 < D_; k0 += 16) {
#pragma unroll
        for (int it = 0; it < 2; ++it) {
            int lin = tid + it * 256;
            int row = lin >> 2;
            int c4  = (lin & 3) << 2;
            float4 a = *reinterpret_cast<const float4*>(
                &Q[(bN + n0 + row) * D_ + k0 + c4]);
            As[(c4 + 0) * 128 + row] = a.x; As[(c4 + 1) * 128 + row] = a.y;
            As[(c4 + 2) * 128 + row] = a.z; As[(c4 + 3) * 128 + row] = a.w;
            float4 kv = *reinterpret_cast<const float4*>(
                &Km[(bN + m0 + row) * D_ + k0 + c4]);
            Bs[(c4 + 0) * 128 + row] = kv.x; Bs[(c4 + 1) * 128 + row] = kv.y;
            Bs[(c4 + 2) * 128 + row] = kv.z; Bs[(c4 + 3) * 128 + row] = kv.w;
        }
        __syncthreads();
#pragma unroll 4
        for (int kk = 0; kk < 16; ++kk) {
            float4 a0 = *reinterpret_cast<const float4*>(&As[kk * 128 + ty * 8]);
            float4 a1 = *reinterpret_cast<const float4*>(&As[kk * 128 + ty * 8 + 4]);
            float4 b0 = *reinterpret_cast<const float4*>(&Bs[kk * 128 + tx * 4]);
            float4 b1 = *reinterpret_cast<const float4*>(&Bs[kk * 128 + 64 + tx * 4]);
            float av[8] = {a0.x,a0.y,a0.z,a0.w,a1.x,a1.y,a1.z,a1.w};
            float bv[8] = {b0.x,b0.y,b0.z,b0.w,b1.x,b1.y,b1.z,b1.w};
#pragma unroll
            for (int i = 0; i < 8; ++i)
#pragma unroll
                for (int j = 0; j < 8; ++j)
                    acc[i][j] = fmaf(av[i], bv[j], acc[i][j]);
        }
        __syncthreads();
    }

    // ---- fold to per-row top-8 over this chunk, 4 passes of 32 rows ----
    const int myp = ty >> 2;             // which pass owns this thread's rows
    for (int p = 0; p < 4; ++p) {
        if (myp == p) {
#pragma unroll
            for (int i = 0; i < 8; ++i) {
                int rloc = (ty & 3) * 8 + i;       // row - p*32
                int n = n0 + ty * 8 + i;
#pragma unroll
                for (int j = 0; j < 8; ++j) {
                    int col = (j < 4) ? (tx * 4 + j) : (64 + tx * 4 + (j - 4));
                    int m = m0 + col;
                    bool ok = (m <= n);
                    MV[rloc * 128 + tx * 8 + j] =
                        ok ? (acc[i][j] * SCALE_ + ALPHA_ * Ps[col]) : -INFINITY;
                    MI[rloc * 128 + tx * 8 + j] = ok ? m : 0x7fffffff;
                }
            }
        }
        __syncthreads();
        if (tid < 32) {
            float tv[KTOP]; int ti[KTOP];
#pragma unroll
            for (int j = 0; j < KTOP; ++j) { tv[j] = -INFINITY; ti[j] = 0x7fffffff; }
            for (int i2 = 0; i2 < 128; ++i2) {
                float s = MV[tid * 128 + i2];
                if (s == -INFINITY) continue;
                topk_insert(tv, ti, s, MI[tid * 128 + i2]);
            }
            int n = n0 + p * 32 + tid;
            size_t base = ((bN + n) * NCH + ch) * 8;
#pragma unroll
            for (int j = 0; j < KTOP; ++j) { WV[base + j] = tv[j]; WI[base + j] = ti[j]; }
        }
        __syncthreads();
    }
}

// ---------------------------------------------------------------------------
// attn_merge: per row, merge <=16 chunk lists (<=128 candidates) -> global
// top-8 -> softmax -> gather V -> CC[:, D:2D]. Grid 2048 blocks, 4 rows each.
// ---------------------------------------------------------------------------
__global__ __launch_bounds__(256)
void attn_merge(const float* __restrict__ WV, const int* __restrict__ WI,
                const float* __restrict__ V, float* __restrict__ CC)
{
    __shared__ float CV[4][128];
    __shared__ int   CI[4][128];
    __shared__ float Pp[4][KTOP];
    __shared__ int   Pi[4][KTOP];

    const int tid  = threadIdx.x;
    const int wv   = tid >> 6;
    const int lane = tid & 63;
    const int rid  = blockIdx.x * 4 + wv;     // 0..8191
    const int b    = rid >> 11;
    const int n    = rid & (N_ - 1);
    const int ncand = ((n >> 7) + 1) * 8;     // 8..128
    const size_t cbase = (size_t)rid * (NCH * 8);   // [b][n][NCH][8] flat

#pragma unroll
    for (int t = 0; t < 2; ++t) {
        int i = lane + t * 64;
        if (i < ncand) { CV[wv][i] = WV[cbase + i]; CI[wv][i] = WI[cbase + i]; }
        else           { CV[wv][i] = -INFINITY;     CI[wv][i] = 0x7fffffff;   }
    }
    __syncthreads();

    if (lane == 0) {
        float tv[KTOP]; int ti[KTOP];
#pragma unroll
        for (int j = 0; j < KTOP; ++j) { tv[j] = -INFINITY; ti[j] = 0x7fffffff; }
        for (int i = 0; i < 128; ++i) {
            float s = CV[wv][i];
            if (s == -INFINITY) continue;
            topk_insert(tv, ti, s, CI[wv][i]);
        }
        float mx = tv[0];
        float e[KTOP]; float sum = 0.f;
#pragma unroll
        for (int j = 0; j < KTOP; ++j) {
            e[j] = (tv[j] == -INFINITY) ? 0.f : __expf(tv[j] - mx);
            sum += e[j];
        }
        float inv = 1.f / sum;
#pragma unroll
        for (int j = 0; j < KTOP; ++j) {
            Pp[wv][j] = e[j] * inv;
            Pi[wv][j] = (tv[j] == -INFINITY) ? 0 : ti[j];
        }
    }
    __syncthreads();

    const float4* V4 = reinterpret_cast<const float4*>(V);
    const size_t vrow = (size_t)b * N_ * 256;            // f4 per row = 256
#pragma unroll
    for (int it = 0; it < 4; ++it) {
        int d4 = it * 64 + lane;
        float ox = 0.f, oy = 0.f, oz = 0.f, ow = 0.f;
#pragma unroll
        for (int j = 0; j < KTOP; ++j) {
            float p = Pp[wv][j];
            float4 v = V4[vrow + (size_t)Pi[wv][j] * 256 + d4];
            ox = fmaf(p, v.x, ox); oy = fmaf(p, v.y, oy);
            oz = fmaf(p, v.z, oz); ow = fmaf(p, v.w, ow);
        }
        float4 o = make_float4(ox, oy, oz, ow);
        reinterpret_cast<float4*>(CC)[(size_t)rid * 512 + 256 + d4] = o;
    }
}

// ---------------------------------------------------------------------------
extern "C" void kernel_launch(void* const* d_in, const int* in_sizes, int n_in,
                              void* d_out, int out_size, void* d_ws, size_t ws_size,
                              hipStream_t stream)
{
    const float* mu   = (const float*)d_in[0];
    const float* pher = (const float*)d_in[1];
    const float* Wq   = (const float*)d_in[2];
    const float* bq   = (const float*)d_in[3];
    const float* Wk   = (const float*)d_in[4];
    const float* bk   = (const float*)d_in[5];
    const float* Wv   = (const float*)d_in[6];
    const float* bv   = (const float*)d_in[7];
    const float* Wm1  = (const float*)d_in[8];
    const float* bm1  = (const float*)d_in[9];
    const float* Wm2  = (const float*)d_in[10];
    const float* bm2  = (const float*)d_in[11];
    const float* Wo   = (const float*)d_in[12];
    const float* bo   = (const float*)d_in[13];
    float* out = (float*)d_out;
    float* ws  = (float*)d_ws;

    const size_t SZ = (size_t)B_ * N_ * D_;     // 8388608
    const int M = B_ * N_;                      // 8192
    float* Qb = ws;
    float* Kb = ws + SZ;
    float* Vb = ws + 2 * SZ;
    float* Ab = ws + 3 * SZ;        // self pre-act -> S; dead after local GEMM
    float* Nb = ws + 4 * SZ;        // neighbor pre-act; dead after silu
    float* CC = ws + 4 * SZ;        // (M x 2D) concat buffer, overlaps dead Nb
    float* WVb = Ab;                // topk vals [M][16][8] = 4MB (Ab dead)
    int*   WIb = (int*)(Ab + (size_t)M * NCH * 8);   // topk idx, 4MB

    dim3 blk(256);
    dim3 gg(1024 / 128, M / 128);   // (8, 64)

    hipLaunchKernelGGL(gemm_bias, gg, blk, 0, stream, mu, Wq, bq, Qb, M, D_, D_, D_);
    hipLaunchKernelGGL(gemm_bias, gg, blk, 0, stream, mu, Wk, bk, Kb, M, D_, D_, D_);
    hipLaunchKernelGGL(gemm_bias, gg, blk, 0, stream, mu, Wv, bv, Vb, M, D_, D_, D_);
    hipLaunchKernelGGL(gemm_bias, gg, blk, 0, stream, mu, Wm1, bm1, Ab, M, D_, D_, D_);
    hipLaunchKernelGGL(gemm_bias, gg, blk, 0, stream, mu, Wm1 + (size_t)D_ * D_,
                       (const float*)nullptr, Nb, M, D_, D_, D_);

    hipLaunchKernelGGL(silu_mean, dim3(SZ / 4 / 256), blk, 0, stream, Ab, Nb);

    // local msgs -> CC[:, 0:D]   (Nb dead; Ab consumed here, dead after)
    hipLaunchKernelGGL(gemm_bias, gg, blk, 0, stream, Ab, Wm2, bm2, CC, M, D_, D_, 2 * D_);

    // scores + per-chunk top-8 -> WVb/WIb (in dead Ab region)
    hipLaunchKernelGGL(attn_scores, dim3(136, B_), blk, 0, stream, Qb, Kb, pher, WVb, WIb);

    // merge + softmax + V gather -> CC[:, D:2D]
    hipLaunchKernelGGL(attn_merge, dim3(M / 4), blk, 0, stream, WVb, WIb, Vb, CC);

    // out = CC @ Wo + bo
    hipLaunchKernelGGL(gemm_bias, gg, blk, 0, stream, CC, Wo, bo, out, M, 2 * D_, D_, D_);

    (void)in_sizes; (void)n_in; (void)out_size; (void)ws_size;
}

// Round 5
// 1621.915 us; speedup vs baseline: 2.0585x; 1.5744x over previous
//
#include <hip/hip_runtime.h>
#include <hip/hip_bf16.h>
#include <math.h>

#define B_ 4
#define N_ 2048
#define D_ 1024
#define WIN_ 4
#define KTOP 8
#define ALPHA_ 0.3f
#define SCALE_ (1.0f/32.0f)
#define NCH 16          // N_/128 col chunks

typedef unsigned short ushortT;
typedef __attribute__((ext_vector_type(8))) short short8v;   // 8 bf16 (4 VGPR)
typedef __attribute__((ext_vector_type(4))) float f32x4;

__device__ inline ushortT f2b(float f) {     // f32 -> bf16 RNE
    unsigned int u = __float_as_uint(f);
    unsigned int r = (u + 0x7fffu + ((u >> 16) & 1u)) >> 16;
    return (ushortT)r;
}

// ---------------------------------------------------------------------------
// f32 -> bf16 elementwise (8 per thread)
// ---------------------------------------------------------------------------
__global__ __launch_bounds__(256)
void f32_to_bf16_k(const float* __restrict__ src, ushortT* __restrict__ dst)
{
    size_t i = ((size_t)blockIdx.x * 256 + threadIdx.x) * 8;
    float4 v0 = *reinterpret_cast<const float4*>(&src[i]);
    float4 v1 = *reinterpret_cast<const float4*>(&src[i + 4]);
    ushort4 a = {f2b(v0.x), f2b(v0.y), f2b(v0.z), f2b(v0.w)};
    ushort4 b = {f2b(v1.x), f2b(v1.y), f2b(v1.z), f2b(v1.w)};
    *reinterpret_cast<ushort4*>(&dst[i])     = a;
    *reinterpret_cast<ushort4*>(&dst[i + 4]) = b;
}

// ---------------------------------------------------------------------------
// W [K][Nn] f32  ->  Wt [Nn][K] bf16  (transpose + convert), 32x32 tiles
// ---------------------------------------------------------------------------
__global__ __launch_bounds__(256)
void transpose_f2b(const float* __restrict__ W, ushortT* __restrict__ Wt,
                   int K, int Nn)
{
    __shared__ float t[32][33];
    const int k0 = blockIdx.x * 32, n0 = blockIdx.y * 32;
    const int tx = threadIdx.x & 31, ty8 = threadIdx.x >> 5;
#pragma unroll
    for (int p = 0; p < 4; ++p) {
        int kk = p * 8 + ty8;
        t[kk][tx] = W[(size_t)(k0 + kk) * Nn + n0 + tx];
    }
    __syncthreads();
#pragma unroll
    for (int p = 0; p < 4; ++p) {
        int nn = p * 8 + ty8;
        Wt[(size_t)(n0 + nn) * K + k0 + tx] = f2b(t[tx][nn]);
    }
}

// ---------------------------------------------------------------------------
// bf16 MFMA GEMM: C[M x 128*gridX] = A[M x K](bf16,lda) @ Bt[N x K](bf16,ldb)^T
// + bias. 128x128 tile, BK=64, 4 waves each computing 64x64.
// LDS rows padded to 72 ushorts (144B) -> 2-way bank aliasing (free).
// A/B frag: row=lane&15, k-group=(lane>>4)*8 (identical for both operands ->
// any k-permutation cancels). C/D: col=lane&15, row=(lane>>4)*4+reg (m89).
// ---------------------------------------------------------------------------
template<int BF16OUT>
__global__ __launch_bounds__(256)
void mfma_gemm(const ushortT* __restrict__ A, int lda,
               const ushortT* __restrict__ Bt, int ldb,
               const float* __restrict__ bias,
               void* __restrict__ Cout, int ldc, int K)
{
    __shared__ ushortT AsL[128 * 72];
    __shared__ ushortT BsL[128 * 72];
    const int tid = threadIdx.x;
    const int m0 = blockIdx.y * 128;
    const int n0 = blockIdx.x * 128;
    const int w = tid >> 6, lane = tid & 63;
    const int wr = w >> 1, wc = w & 1;

    f32x4 acc[4][4];
#pragma unroll
    for (int mi = 0; mi < 4; ++mi)
#pragma unroll
        for (int ni = 0; ni < 4; ++ni) acc[mi][ni] = (f32x4){0.f, 0.f, 0.f, 0.f};

    for (int k0 = 0; k0 < K; k0 += 64) {
#pragma unroll
        for (int it = 0; it < 4; ++it) {     // stage 128x64 bf16 tiles (A and Bt)
            int idx = tid + it * 256;        // 0..1023
            int row = idx >> 3, c = idx & 7; // c*8 in [0,64)
            int4 va = *reinterpret_cast<const int4*>(&A[(size_t)(m0 + row) * lda + k0 + c * 8]);
            *reinterpret_cast<int4*>(&AsL[row * 72 + c * 8]) = va;
            int4 vb = *reinterpret_cast<const int4*>(&Bt[(size_t)(n0 + row) * ldb + k0 + c * 8]);
            *reinterpret_cast<int4*>(&BsL[row * 72 + c * 8]) = vb;
        }
        __syncthreads();
#pragma unroll
        for (int kh = 0; kh < 2; ++kh) {
            const int ko = kh * 32 + (lane >> 4) * 8;
            const int rr = lane & 15;
            short8v af[4], bf[4];
#pragma unroll
            for (int mi = 0; mi < 4; ++mi)
                af[mi] = *reinterpret_cast<const short8v*>(&AsL[(wr * 64 + mi * 16 + rr) * 72 + ko]);
#pragma unroll
            for (int ni = 0; ni < 4; ++ni)
                bf[ni] = *reinterpret_cast<const short8v*>(&BsL[(wc * 64 + ni * 16 + rr) * 72 + ko]);
#pragma unroll
            for (int mi = 0; mi < 4; ++mi)
#pragma unroll
                for (int ni = 0; ni < 4; ++ni)
                    acc[mi][ni] = __builtin_amdgcn_mfma_f32_16x16x32_bf16(
                        af[mi], bf[ni], acc[mi][ni], 0, 0, 0);
        }
        __syncthreads();
    }

    const int r4 = (lane >> 4) * 4, cl = lane & 15;
#pragma unroll
    for (int mi = 0; mi < 4; ++mi)
#pragma unroll
        for (int ni = 0; ni < 4; ++ni) {
            int row = m0 + wr * 64 + mi * 16 + r4;
            int col = n0 + wc * 64 + ni * 16 + cl;
            float bb = bias ? bias[col] : 0.f;
#pragma unroll
            for (int r = 0; r < 4; ++r) {
                float v = acc[mi][ni][r] + bb;
                if (BF16OUT)
                    ((ushortT*)Cout)[(size_t)(row + r) * ldc + col] = f2b(v);
                else
                    ((float*)Cout)[(size_t)(row + r) * ldc + col] = v;
            }
        }
}

// ---------------------------------------------------------------------------
// Generic f32 GEMM (Q/K projections only — feeds top-k, must stay f32).
// ---------------------------------------------------------------------------
__global__ __launch_bounds__(256)
void gemm_bias(const float* __restrict__ X, const float* __restrict__ W,
               const float* __restrict__ bias, float* __restrict__ C,
               int M, int K, int Nc, int ldc)
{
    __shared__ float As[16][128];
    __shared__ float Bs[16][128];
    const int tid = threadIdx.x;
    const int tx = tid & 15;
    const int ty = tid >> 4;
    const int m0 = blockIdx.y * 128;
    const int n0 = blockIdx.x * 128;

    float acc[8][8];
#pragma unroll
    for (int i = 0; i < 8; ++i)
#pragma unroll
        for (int j = 0; j < 8; ++j) acc[i][j] = 0.f;

    for (int k0 = 0; k0 < K; k0 += 16) {
#pragma unroll
        for (int it = 0; it < 2; ++it) {
            int lin = tid + it * 256;
            int row = lin >> 2;
            int c4  = (lin & 3) << 2;
            float4 a = *reinterpret_cast<const float4*>(&X[(size_t)(m0 + row) * K + k0 + c4]);
            As[c4 + 0][row] = a.x; As[c4 + 1][row] = a.y;
            As[c4 + 2][row] = a.z; As[c4 + 3][row] = a.w;
        }
#pragma unroll
        for (int it = 0; it < 2; ++it) {
            int lin = tid + it * 256;
            int kk = lin >> 5;
            int c4 = (lin & 31) << 2;
            *reinterpret_cast<float4*>(&Bs[kk][c4]) =
                *reinterpret_cast<const float4*>(&W[(size_t)(k0 + kk) * Nc + n0 + c4]);
        }
        __syncthreads();
#pragma unroll 4
        for (int kk = 0; kk < 16; ++kk) {
            float4 a0 = *reinterpret_cast<const float4*>(&As[kk][ty * 8]);
            float4 a1 = *reinterpret_cast<const float4*>(&As[kk][ty * 8 + 4]);
            float4 b0 = *reinterpret_cast<const float4*>(&Bs[kk][tx * 4]);
            float4 b1 = *reinterpret_cast<const float4*>(&Bs[kk][64 + tx * 4]);
            float av[8] = {a0.x,a0.y,a0.z,a0.w,a1.x,a1.y,a1.z,a1.w};
            float bv[8] = {b0.x,b0.y,b0.z,b0.w,b1.x,b1.y,b1.z,b1.w};
#pragma unroll
            for (int i = 0; i < 8; ++i)
#pragma unroll
                for (int j = 0; j < 8; ++j)
                    acc[i][j] = fmaf(av[i], bv[j], acc[i][j]);
        }
        __syncthreads();
    }
    float4 bb0 = make_float4(0.f,0.f,0.f,0.f), bb1 = make_float4(0.f,0.f,0.f,0.f);
    if (bias) {
        bb0 = *reinterpret_cast<const float4*>(&bias[n0 + tx * 4]);
        bb1 = *reinterpret_cast<const float4*>(&bias[n0 + 64 + tx * 4]);
    }
#pragma unroll
    for (int i = 0; i < 8; ++i) {
        size_t row = (size_t)(m0 + ty * 8 + i);
        float4 o0 = make_float4(acc[i][0]+bb0.x, acc[i][1]+bb0.y, acc[i][2]+bb0.z, acc[i][3]+bb0.w);
        float4 o1 = make_float4(acc[i][4]+bb1.x, acc[i][5]+bb1.y, acc[i][6]+bb1.z, acc[i][7]+bb1.w);
        *reinterpret_cast<float4*>(&C[row * ldc + n0 + tx * 4]) = o0;
        *reinterpret_cast<float4*>(&C[row * ldc + n0 + 64 + tx * 4]) = o1;
    }
}

// ---------------------------------------------------------------------------
// S[b,n,:] = mean_w silu(A + Nb shifted), output bf16.
// ---------------------------------------------------------------------------
__global__ __launch_bounds__(256)
void silu_mean(const float* __restrict__ A, const float* __restrict__ Nb,
               ushortT* __restrict__ Sb)
{
    size_t idx4 = (size_t)blockIdx.x * blockDim.x + threadIdx.x;
    size_t base = idx4 << 2;
    int n = (int)((base >> 10) & (N_ - 1));
    float4 a = *reinterpret_cast<const float4*>(&A[base]);
    float sx = 0.f, sy = 0.f, sz = 0.f, sw = 0.f;
#pragma unroll
    for (int w = 1; w <= WIN_; ++w) {
        float xx = a.x, xy = a.y, xz = a.z, xw = a.w;
        if (n >= w) {
            const float4 nb = *reinterpret_cast<const float4*>(&Nb[base - (size_t)w * D_]);
            xx += nb.x; xy += nb.y; xz += nb.z; xw += nb.w;
        }
        sx += xx / (1.f + __expf(-xx));
        sy += xy / (1.f + __expf(-xy));
        sz += xz / (1.f + __expf(-xz));
        sw += xw / (1.f + __expf(-xw));
    }
    ushort4 o = {f2b(sx * 0.25f), f2b(sy * 0.25f), f2b(sz * 0.25f), f2b(sw * 0.25f)};
    *reinterpret_cast<ushort4*>(&Sb[base]) = o;
}

// ---------------------------------------------------------------------------
__device__ inline void topk_insert(float (&tv)[KTOP], int (&ti)[KTOP], float s, int m)
{
    if ((s > tv[KTOP-1]) || (s == tv[KTOP-1] && m < ti[KTOP-1])) {
        float cs = s; int ci = m;
#pragma unroll
        for (int q = 0; q < KTOP; ++q) {
            bool beats = (cs > tv[q]) || (cs == tv[q] && ci < ti[q]);
            if (beats) { float t0 = tv[q]; int t1 = ti[q];
                         tv[q] = cs; ti[q] = ci; cs = t0; ci = t1; }
        }
    }
}

// ---------------------------------------------------------------------------
// attn_scores (f32, exact): 512 threads, 8 waves, 128x128 tile, 8x4 microtile.
// Grid (136, B): causal tile enumeration. Per-row top-8 over the chunk.
// ---------------------------------------------------------------------------
__global__ __launch_bounds__(512)
void attn_scores(const float* __restrict__ Q, const float* __restrict__ Km,
                 const float* __restrict__ pher,
                 float* __restrict__ WV, int* __restrict__ WI)
{
    __shared__ char smem[32768];
    float* As = reinterpret_cast<float*>(smem);          // [16][128]
    float* Bs = As + 16 * 128;                           // [16][128]
    float* MV = reinterpret_cast<float*>(smem);          // [32][128] (reuse)
    int*   MI = reinterpret_cast<int*>(smem + 16384);    // [32][128]
    __shared__ float Ps[128];

    const int b = blockIdx.y;
    const int x = blockIdx.x;            // 0..135
    int g = 0;
    while ((g + 1) * (g + 2) / 2 <= x) ++g;
    const int ch = x - g * (g + 1) / 2;
    const int n0 = g * 128;
    const int m0 = ch * 128;
    const int tid = threadIdx.x;
    const int tx = tid & 31;             // 32 col groups x 4 cols
    const int ty = tid >> 5;             // 16 row groups x 8 rows
    const size_t bN = (size_t)b * N_;

    if (tid < 128) Ps[tid] = pher[bN + m0 + tid];

    float acc[8][4];
#pragma unroll
    for (int i = 0; i < 8; ++i)
#pragma unroll
        for (int j = 0; j < 4; ++j) acc[i][j] = 0.f;

    for (int k0 = 0; k0 < D_; k0 += 16) {
        {   // stage both 128x16 tiles, 1 float4 per thread each
            int row = tid >> 2, c4 = (tid & 3) << 2;
            float4 a = *reinterpret_cast<const float4*>(&Q[(bN + n0 + row) * D_ + k0 + c4]);
            As[(c4 + 0) * 128 + row] = a.x; As[(c4 + 1) * 128 + row] = a.y;
            As[(c4 + 2) * 128 + row] = a.z; As[(c4 + 3) * 128 + row] = a.w;
            float4 kv = *reinterpret_cast<const float4*>(&Km[(bN + m0 + row) * D_ + k0 + c4]);
            Bs[(c4 + 0) * 128 + row] = kv.x; Bs[(c4 + 1) * 128 + row] = kv.y;
            Bs[(c4 + 2) * 128 + row] = kv.z; Bs[(c4 + 3) * 128 + row] = kv.w;
        }
        __syncthreads();
#pragma unroll 4
        for (int kk = 0; kk < 16; ++kk) {
            float4 a0 = *reinterpret_cast<const float4*>(&As[kk * 128 + ty * 8]);
            float4 a1 = *reinterpret_cast<const float4*>(&As[kk * 128 + ty * 8 + 4]);
            float4 b0 = *reinterpret_cast<const float4*>(&Bs[kk * 128 + tx * 4]);
            float av[8] = {a0.x,a0.y,a0.z,a0.w,a1.x,a1.y,a1.z,a1.w};
            float bv[4] = {b0.x,b0.y,b0.z,b0.w};
#pragma unroll
            for (int i = 0; i < 8; ++i)
#pragma unroll
                for (int j = 0; j < 4; ++j)
                    acc[i][j] = fmaf(av[i], bv[j], acc[i][j]);
        }
        __syncthreads();
    }

    // fold to per-row top-8: 4 passes of 32 rows
    const int myp = ty >> 2;
    for (int p = 0; p < 4; ++p) {
        if (myp == p) {
#pragma unroll
            for (int i = 0; i < 8; ++i) {
                int rloc = (ty & 3) * 8 + i;
                int n = n0 + ty * 8 + i;
#pragma unroll
                for (int j = 0; j < 4; ++j) {
                    int col = tx * 4 + j;
                    int m = m0 + col;
                    bool ok = (m <= n);
                    MV[rloc * 128 + col] = ok ? (acc[i][j] * SCALE_ + ALPHA_ * Ps[col]) : -INFINITY;
                    MI[rloc * 128 + col] = ok ? m : 0x7fffffff;
                }
            }
        }
        __syncthreads();
        if (tid < 32) {
            float tv[KTOP]; int ti[KTOP];
#pragma unroll
            for (int j = 0; j < KTOP; ++j) { tv[j] = -INFINITY; ti[j] = 0x7fffffff; }
            for (int i2 = 0; i2 < 128; ++i2) {
                float s = MV[tid * 128 + i2];
                if (s == -INFINITY) continue;
                topk_insert(tv, ti, s, MI[tid * 128 + i2]);
            }
            int n = n0 + p * 32 + tid;
            size_t base = ((bN + n) * NCH + ch) * 8;
#pragma unroll
            for (int j = 0; j < KTOP; ++j) { WV[base + j] = tv[j]; WI[base + j] = ti[j]; }
        }
        __syncthreads();
    }
}

// ---------------------------------------------------------------------------
// attn_merge: merge <=16 chunk lists -> top-8 -> softmax -> V gather -> CCb
// (bf16, cols 1024..2047). Grid 2048 blocks, 4 rows each.
// ---------------------------------------------------------------------------
__global__ __launch_bounds__(256)
void attn_merge(const float* __restrict__ WV, const int* __restrict__ WI,
                const float* __restrict__ V, ushortT* __restrict__ CCb)
{
    __shared__ float CV[4][128];
    __shared__ int   CI[4][128];
    __shared__ float Pp[4][KTOP];
    __shared__ int   Pi[4][KTOP];

    const int tid  = threadIdx.x;
    const int wv   = tid >> 6;
    const int lane = tid & 63;
    const int rid  = blockIdx.x * 4 + wv;
    const int b    = rid >> 11;
    const int n    = rid & (N_ - 1);
    const int ncand = ((n >> 7) + 1) * 8;
    const size_t cbase = (size_t)rid * (NCH * 8);

#pragma unroll
    for (int t = 0; t < 2; ++t) {
        int i = lane + t * 64;
        if (i < ncand) { CV[wv][i] = WV[cbase + i]; CI[wv][i] = WI[cbase + i]; }
        else           { CV[wv][i] = -INFINITY;     CI[wv][i] = 0x7fffffff;   }
    }
    __syncthreads();

    if (lane == 0) {
        float tv[KTOP]; int ti[KTOP];
#pragma unroll
        for (int j = 0; j < KTOP; ++j) { tv[j] = -INFINITY; ti[j] = 0x7fffffff; }
        for (int i = 0; i < 128; ++i) {
            float s = CV[wv][i];
            if (s == -INFINITY) continue;
            topk_insert(tv, ti, s, CI[wv][i]);
        }
        float mx = tv[0];
        float e[KTOP]; float sum = 0.f;
#pragma unroll
        for (int j = 0; j < KTOP; ++j) {
            e[j] = (tv[j] == -INFINITY) ? 0.f : __expf(tv[j] - mx);
            sum += e[j];
        }
        float inv = 1.f / sum;
#pragma unroll
        for (int j = 0; j < KTOP; ++j) {
            Pp[wv][j] = e[j] * inv;
            Pi[wv][j] = (tv[j] == -INFINITY) ? 0 : ti[j];
        }
    }
    __syncthreads();

    const float4* V4 = reinterpret_cast<const float4*>(V);
    const size_t vrow = (size_t)b * N_ * 256;
#pragma unroll
    for (int it = 0; it < 4; ++it) {
        int d4 = it * 64 + lane;
        float ox = 0.f, oy = 0.f, oz = 0.f, ow = 0.f;
#pragma unroll
        for (int j = 0; j < KTOP; ++j) {
            float p = Pp[wv][j];
            float4 v = V4[vrow + (size_t)Pi[wv][j] * 256 + d4];
            ox = fmaf(p, v.x, ox); oy = fmaf(p, v.y, oy);
            oz = fmaf(p, v.z, oz); ow = fmaf(p, v.w, ow);
        }
        ushort4 ob = {f2b(ox), f2b(oy), f2b(oz), f2b(ow)};
        *reinterpret_cast<ushort4*>(&CCb[(size_t)rid * 2048 + 1024 + d4 * 4]) = ob;
    }
}

// ---------------------------------------------------------------------------
extern "C" void kernel_launch(void* const* d_in, const int* in_sizes, int n_in,
                              void* d_out, int out_size, void* d_ws, size_t ws_size,
                              hipStream_t stream)
{
    const float* mu   = (const float*)d_in[0];
    const float* pher = (const float*)d_in[1];
    const float* Wq   = (const float*)d_in[2];
    const float* bq   = (const float*)d_in[3];
    const float* Wk   = (const float*)d_in[4];
    const float* bk   = (const float*)d_in[5];
    const float* Wv   = (const float*)d_in[6];
    const float* bv   = (const float*)d_in[7];
    const float* Wm1  = (const float*)d_in[8];
    const float* bm1  = (const float*)d_in[9];
    const float* Wm2  = (const float*)d_in[10];
    const float* bm2  = (const float*)d_in[11];
    const float* Wo   = (const float*)d_in[12];
    const float* bo   = (const float*)d_in[13];
    float* out = (float*)d_out;
    float* ws  = (float*)d_ws;

    const size_t SZ = (size_t)B_ * N_ * D_;     // 8388608
    const int M = B_ * N_;                      // 8192
    const size_t MEG = 1024 * 1024;

    // ---- workspace map (float units), overlapping by liveness ----
    ushortT* CCb  = (ushortT*)ws;                       // [8192][2048] bf16, live to end
    float*   Ab   = ws + SZ;                            // f32 pre-act; dead after silu
    float*   Nbuf = ws + 2 * SZ;                        // dead after silu
    ushortT* mu_b = (ushortT*)(ws + 3 * SZ);            // dead after V gemm
    ushortT* Sb   = (ushortT*)(ws + 3 * SZ + SZ / 2);   // dead after local gemm
    ushortT* Wt_m1 = (ushortT*)(ws + 4 * SZ);           // [1024][2048] bf16
    ushortT* Wt_m2 = Wt_m1 + 2 * MEG;                   // [1024][1024]
    ushortT* Wt_v  = Wt_m2 + MEG;                       // [1024][1024]
    float*   Vb    = ws + 4 * SZ + 2 * MEG;             // f32 [8192][1024]
    // phase-2 overlays:
    float*   Qb  = Ab;                                  // after silu
    float*   Kb  = Nbuf;
    float*   WVb = (float*)Sb;                          // [M][16][8] f32 (1M floats)
    int*     WIb = (int*)(WVb + MEG);                   // 1M ints
    ushortT* Wt_o = mu_b;                               // [1024][2048] bf16 (after V gemm)

    dim3 blk256(256), blk512(512);
    dim3 gD(8, 64);                 // 128x128 tiles over (1024, 8192)

    // ---- local path (bf16 MFMA) ----
    hipLaunchKernelGGL(f32_to_bf16_k, dim3(SZ / 8 / 256), blk256, 0, stream, mu, mu_b);
    hipLaunchKernelGGL(transpose_f2b, dim3(64, 32), blk256, 0, stream, Wm1, Wt_m1, 2048, 1024);
    hipLaunchKernelGGL(transpose_f2b, dim3(32, 32), blk256, 0, stream, Wm2, Wt_m2, 1024, 1024);
    hipLaunchKernelGGL((mfma_gemm<0>), gD, blk256, 0, stream,
                       mu_b, D_, Wt_m1, 2048, bm1, (void*)Ab, D_, D_);
    hipLaunchKernelGGL((mfma_gemm<0>), gD, blk256, 0, stream,
                       mu_b, D_, Wt_m1 + 1024, 2048, (const float*)nullptr, (void*)Nbuf, D_, D_);
    hipLaunchKernelGGL(silu_mean, dim3(SZ / 4 / 256), blk256, 0, stream, Ab, Nbuf, Sb);
    hipLaunchKernelGGL((mfma_gemm<1>), gD, blk256, 0, stream,
                       Sb, D_, Wt_m2, D_, bm2, (void*)CCb, 2 * D_, D_);

    // ---- V (bf16 MFMA, f32 out) ----
    hipLaunchKernelGGL(transpose_f2b, dim3(32, 32), blk256, 0, stream, Wv, Wt_v, 1024, 1024);
    hipLaunchKernelGGL((mfma_gemm<0>), gD, blk256, 0, stream,
                       mu_b, D_, Wt_v, D_, bv, (void*)Vb, D_, D_);
    hipLaunchKernelGGL(transpose_f2b, dim3(64, 32), blk256, 0, stream, Wo, Wt_o, 2048, 1024);

    // ---- Q/K (f32, exact — feeds top-k) ----
    hipLaunchKernelGGL(gemm_bias, gD, blk256, 0, stream, mu, Wq, bq, Qb, M, D_, D_, D_);
    hipLaunchKernelGGL(gemm_bias, gD, blk256, 0, stream, mu, Wk, bk, Kb, M, D_, D_, D_);

    // ---- scores + top-k + gather ----
    hipLaunchKernelGGL(attn_scores, dim3(136, B_), blk512, 0, stream, Qb, Kb, pher, WVb, WIb);
    hipLaunchKernelGGL(attn_merge, dim3(M / 4), blk256, 0, stream, WVb, WIb, Vb, CCb);

    // ---- out = CCb @ Wo + bo (bf16 MFMA, K=2048) ----
    hipLaunchKernelGGL((mfma_gemm<0>), gD, blk256, 0, stream,
                       CCb, 2 * D_, Wt_o, 2048, bo, (void*)out, D_, 2 * D_);

    (void)in_sizes; (void)n_in; (void)out_size; (void)ws_size;
}

// Round 6
// 1456.599 us; speedup vs baseline: 2.2921x; 1.1135x over previous
//
#include <hip/hip_runtime.h>
#include <hip/hip_bf16.h>
#include <math.h>

#define B_ 4
#define N_ 2048
#define D_ 1024
#define WIN_ 4
#define KTOP 8
#define ALPHA_ 0.3f
#define SCALE_ (1.0f/32.0f)
#define NCH 16          // N_/128 col chunks
#define LDSROW 36       // ushorts per LDS tile row (72B stride: conflict-free)

typedef unsigned short ushortT;
typedef __attribute__((ext_vector_type(8))) short short8v;   // 8 bf16 (4 VGPR)
typedef __attribute__((ext_vector_type(4))) float f32x4;

__device__ inline ushortT f2b(float f) {     // f32 -> bf16 RNE
    unsigned int u = __float_as_uint(f);
    unsigned int r = (u + 0x7fffu + ((u >> 16) & 1u)) >> 16;
    return (ushortT)r;
}
__device__ inline float b2f(ushortT u) {
    return __uint_as_float(((unsigned int)u) << 16);
}

// ---------------------------------------------------------------------------
// f32 -> bf16 elementwise (8 per thread)
// ---------------------------------------------------------------------------
__global__ __launch_bounds__(256)
void f32_to_bf16_k(const float* __restrict__ src, ushortT* __restrict__ dst)
{
    size_t i = ((size_t)blockIdx.x * 256 + threadIdx.x) * 8;
    float4 v0 = *reinterpret_cast<const float4*>(&src[i]);
    float4 v1 = *reinterpret_cast<const float4*>(&src[i + 4]);
    ushort4 a = {f2b(v0.x), f2b(v0.y), f2b(v0.z), f2b(v0.w)};
    ushort4 b = {f2b(v1.x), f2b(v1.y), f2b(v1.z), f2b(v1.w)};
    *reinterpret_cast<ushort4*>(&dst[i])     = a;
    *reinterpret_cast<ushort4*>(&dst[i + 4]) = b;
}

// ---------------------------------------------------------------------------
// W [K][Nn] f32  ->  Wt [Nn][K] bf16  (transpose + convert), 32x32 tiles
// ---------------------------------------------------------------------------
__global__ __launch_bounds__(256)
void transpose_f2b(const float* __restrict__ W, ushortT* __restrict__ Wt,
                   int K, int Nn)
{
    __shared__ float t[32][33];
    const int k0 = blockIdx.x * 32, n0 = blockIdx.y * 32;
    const int tx = threadIdx.x & 31, ty8 = threadIdx.x >> 5;
#pragma unroll
    for (int p = 0; p < 4; ++p) {
        int kk = p * 8 + ty8;
        t[kk][tx] = W[(size_t)(k0 + kk) * Nn + n0 + tx];
    }
    __syncthreads();
#pragma unroll
    for (int p = 0; p < 4; ++p) {
        int nn = p * 8 + ty8;
        Wt[(size_t)(n0 + nn) * K + k0 + tx] = f2b(t[tx][nn]);
    }
}

// ---------------------------------------------------------------------------
// bf16 MFMA GEMM (proven R5): 128x128 tile, BK=64, 4 waves, 64x64/wave.
// ---------------------------------------------------------------------------
template<int BF16OUT>
__global__ __launch_bounds__(256)
void mfma_gemm(const ushortT* __restrict__ A, int lda,
               const ushortT* __restrict__ Bt, int ldb,
               const float* __restrict__ bias,
               void* __restrict__ Cout, int ldc, int K)
{
    __shared__ ushortT AsL[128 * 72];
    __shared__ ushortT BsL[128 * 72];
    const int tid = threadIdx.x;
    const int m0 = blockIdx.y * 128;
    const int n0 = blockIdx.x * 128;
    const int w = tid >> 6, lane = tid & 63;
    const int wr = w >> 1, wc = w & 1;

    f32x4 acc[4][4];
#pragma unroll
    for (int mi = 0; mi < 4; ++mi)
#pragma unroll
        for (int ni = 0; ni < 4; ++ni) acc[mi][ni] = (f32x4){0.f, 0.f, 0.f, 0.f};

    for (int k0 = 0; k0 < K; k0 += 64) {
#pragma unroll
        for (int it = 0; it < 4; ++it) {
            int idx = tid + it * 256;        // 0..1023
            int row = idx >> 3, c = idx & 7;
            int4 va = *reinterpret_cast<const int4*>(&A[(size_t)(m0 + row) * lda + k0 + c * 8]);
            *reinterpret_cast<int4*>(&AsL[row * 72 + c * 8]) = va;
            int4 vb = *reinterpret_cast<const int4*>(&Bt[(size_t)(n0 + row) * ldb + k0 + c * 8]);
            *reinterpret_cast<int4*>(&BsL[row * 72 + c * 8]) = vb;
        }
        __syncthreads();
#pragma unroll
        for (int kh = 0; kh < 2; ++kh) {
            const int ko = kh * 32 + (lane >> 4) * 8;
            const int rr = lane & 15;
            short8v af[4], bf[4];
#pragma unroll
            for (int mi = 0; mi < 4; ++mi)
                af[mi] = *reinterpret_cast<const short8v*>(&AsL[(wr * 64 + mi * 16 + rr) * 72 + ko]);
#pragma unroll
            for (int ni = 0; ni < 4; ++ni)
                bf[ni] = *reinterpret_cast<const short8v*>(&BsL[(wc * 64 + ni * 16 + rr) * 72 + ko]);
#pragma unroll
            for (int mi = 0; mi < 4; ++mi)
#pragma unroll
                for (int ni = 0; ni < 4; ++ni)
                    acc[mi][ni] = __builtin_amdgcn_mfma_f32_16x16x32_bf16(
                        af[mi], bf[ni], acc[mi][ni], 0, 0, 0);
        }
        __syncthreads();
    }

    const int r4 = (lane >> 4) * 4, cl = lane & 15;
#pragma unroll
    for (int mi = 0; mi < 4; ++mi)
#pragma unroll
        for (int ni = 0; ni < 4; ++ni) {
            int row = m0 + wr * 64 + mi * 16 + r4;
            int col = n0 + wc * 64 + ni * 16 + cl;
            float bb = bias ? bias[col] : 0.f;
#pragma unroll
            for (int r = 0; r < 4; ++r) {
                float v = acc[mi][ni][r] + bb;
                if (BF16OUT)
                    ((ushortT*)Cout)[(size_t)(row + r) * ldc + col] = f2b(v);
                else
                    ((float*)Cout)[(size_t)(row + r) * ldc + col] = v;
            }
        }
}

// ---------------------------------------------------------------------------
// f32 GEMM + 3-way bf16 split epilogue: computes X@W+bias exactly in f32,
// then writes planes a=bf16(v), b=bf16(v-a), c=bf16(v-a-b). (Q/K projections.)
// ---------------------------------------------------------------------------
__global__ __launch_bounds__(256)
void gemm_bias_split3(const float* __restrict__ X, const float* __restrict__ W,
                      const float* __restrict__ bias,
                      ushortT* __restrict__ Pa, ushortT* __restrict__ Pb,
                      ushortT* __restrict__ Pc, int K, int Nc)
{
    __shared__ float As[16][128];
    __shared__ float Bs[16][128];
    const int tid = threadIdx.x;
    const int tx = tid & 15;
    const int ty = tid >> 4;
    const int m0 = blockIdx.y * 128;
    const int n0 = blockIdx.x * 128;

    float acc[8][8];
#pragma unroll
    for (int i = 0; i < 8; ++i)
#pragma unroll
        for (int j = 0; j < 8; ++j) acc[i][j] = 0.f;

    for (int k0 = 0; k0 < K; k0 += 16) {
#pragma unroll
        for (int it = 0; it < 2; ++it) {
            int lin = tid + it * 256;
            int row = lin >> 2;
            int c4  = (lin & 3) << 2;
            float4 a = *reinterpret_cast<const float4*>(&X[(size_t)(m0 + row) * K + k0 + c4]);
            As[c4 + 0][row] = a.x; As[c4 + 1][row] = a.y;
            As[c4 + 2][row] = a.z; As[c4 + 3][row] = a.w;
        }
#pragma unroll
        for (int it = 0; it < 2; ++it) {
            int lin = tid + it * 256;
            int kk = lin >> 5;
            int c4 = (lin & 31) << 2;
            *reinterpret_cast<float4*>(&Bs[kk][c4]) =
                *reinterpret_cast<const float4*>(&W[(size_t)(k0 + kk) * Nc + n0 + c4]);
        }
        __syncthreads();
#pragma unroll 4
        for (int kk = 0; kk < 16; ++kk) {
            float4 a0 = *reinterpret_cast<const float4*>(&As[kk][ty * 8]);
            float4 a1 = *reinterpret_cast<const float4*>(&As[kk][ty * 8 + 4]);
            float4 b0 = *reinterpret_cast<const float4*>(&Bs[kk][tx * 4]);
            float4 b1 = *reinterpret_cast<const float4*>(&Bs[kk][64 + tx * 4]);
            float av[8] = {a0.x,a0.y,a0.z,a0.w,a1.x,a1.y,a1.z,a1.w};
            float bv[8] = {b0.x,b0.y,b0.z,b0.w,b1.x,b1.y,b1.z,b1.w};
#pragma unroll
            for (int i = 0; i < 8; ++i)
#pragma unroll
                for (int j = 0; j < 8; ++j)
                    acc[i][j] = fmaf(av[i], bv[j], acc[i][j]);
        }
        __syncthreads();
    }

#pragma unroll
    for (int i = 0; i < 8; ++i) {
        size_t row = (size_t)(m0 + ty * 8 + i);
#pragma unroll
        for (int half = 0; half < 2; ++half) {
            int colbase = n0 + half * 64 + tx * 4;
            ushort4 pa, pb, pc;
#pragma unroll
            for (int j = 0; j < 4; ++j) {
                float v = acc[i][half * 4 + j] + (bias ? bias[colbase + j] : 0.f);
                ushortT a = f2b(v);  float r1 = v - b2f(a);
                ushortT b = f2b(r1); float r2 = r1 - b2f(b);
                ushortT c = f2b(r2);
                ((ushortT*)&pa)[j] = a; ((ushortT*)&pb)[j] = b; ((ushortT*)&pc)[j] = c;
            }
            *reinterpret_cast<ushort4*>(&Pa[row * D_ + colbase]) = pa;
            *reinterpret_cast<ushort4*>(&Pb[row * D_ + colbase]) = pb;
            *reinterpret_cast<ushort4*>(&Pc[row * D_ + colbase]) = pc;
        }
    }
}

// ---------------------------------------------------------------------------
// S[b,n,:] = mean_w silu(A + Nb shifted), output bf16.
// ---------------------------------------------------------------------------
__global__ __launch_bounds__(256)
void silu_mean(const float* __restrict__ A, const float* __restrict__ Nb,
               ushortT* __restrict__ Sb)
{
    size_t idx4 = (size_t)blockIdx.x * blockDim.x + threadIdx.x;
    size_t base = idx4 << 2;
    int n = (int)((base >> 10) & (N_ - 1));
    float4 a = *reinterpret_cast<const float4*>(&A[base]);
    float sx = 0.f, sy = 0.f, sz = 0.f, sw = 0.f;
#pragma unroll
    for (int w = 1; w <= WIN_; ++w) {
        float xx = a.x, xy = a.y, xz = a.z, xw = a.w;
        if (n >= w) {
            const float4 nb = *reinterpret_cast<const float4*>(&Nb[base - (size_t)w * D_]);
            xx += nb.x; xy += nb.y; xz += nb.z; xw += nb.w;
        }
        sx += xx / (1.f + __expf(-xx));
        sy += xy / (1.f + __expf(-xy));
        sz += xz / (1.f + __expf(-xz));
        sw += xw / (1.f + __expf(-xw));
    }
    ushort4 o = {f2b(sx * 0.25f), f2b(sy * 0.25f), f2b(sz * 0.25f), f2b(sw * 0.25f)};
    *reinterpret_cast<ushort4*>(&Sb[base]) = o;
}

// ---------------------------------------------------------------------------
__device__ inline void topk_insert(float (&tv)[KTOP], int (&ti)[KTOP], float s, int m)
{
    if ((s > tv[KTOP-1]) || (s == tv[KTOP-1] && m < ti[KTOP-1])) {
        float cs = s; int ci = m;
#pragma unroll
        for (int q = 0; q < KTOP; ++q) {
            bool beats = (cs > tv[q]) || (cs == tv[q] && ci < ti[q]);
            if (beats) { float t0 = tv[q]; int t1 = ti[q];
                         tv[q] = cs; ti[q] = ci; cs = t0; ci = t1; }
        }
    }
}

// ---------------------------------------------------------------------------
// attn_scores_mfma: split-precision scores via 6 bf16 MFMA products
// (ah, al, am, bh, bl, ch) accumulated in f32 — f32-equivalent accuracy.
// 128x128 causal tiles (grid (136,B)), 256 threads / 4 waves, BK=32.
// LDS tiles [128][LDSROW=36] -> conflict-free ds_read_b128 frag loads.
// Then per-row top-8 fold (4 passes of 32 rows) as in the proven R5 kernel.
// ---------------------------------------------------------------------------
__global__ __launch_bounds__(256)
void attn_scores_mfma(const ushortT* __restrict__ Qa, const ushortT* __restrict__ Qb2,
                      const ushortT* __restrict__ Qc,
                      const ushortT* __restrict__ Ka, const ushortT* __restrict__ Kb2,
                      const ushortT* __restrict__ Kc,
                      const float* __restrict__ pher,
                      float* __restrict__ WV, int* __restrict__ WI)
{
    __shared__ ushortT tiles[6][128][LDSROW];      // 55296 B
    __shared__ float Ps[128];
    float* MV = reinterpret_cast<float*>(&tiles[0][0][0]);              // [32][128]
    int*   MI = reinterpret_cast<int*>((char*)&tiles[0][0][0] + 16384); // [32][128]

    const int b = blockIdx.y;
    const int x = blockIdx.x;            // 0..135
    int g = 0;
    while ((g + 1) * (g + 2) / 2 <= x) ++g;
    const int ch = x - g * (g + 1) / 2;
    const int n0 = g * 128;
    const int m0 = ch * 128;
    const int tid = threadIdx.x;
    const int w = tid >> 6, lane = tid & 63;
    const int wr = w >> 1, wc = w & 1;
    const size_t bN = (size_t)b * N_;

    if (tid < 128) Ps[tid] = pher[bN + m0 + tid];

    f32x4 acc[4][4];
#pragma unroll
    for (int mi = 0; mi < 4; ++mi)
#pragma unroll
        for (int ni = 0; ni < 4; ++ni) acc[mi][ni] = (f32x4){0.f, 0.f, 0.f, 0.f};

    for (int k0 = 0; k0 < D_; k0 += 32) {
        // stage 6 tiles of 128x32 bf16: 512 int4 each, 2 per thread
#pragma unroll
        for (int t = 0; t < 6; ++t) {
            const ushortT* src = (t == 0) ? Qa : (t == 1) ? Qb2 : (t == 2) ? Qc
                               : (t == 3) ? Ka : (t == 4) ? Kb2 : Kc;
            const int rbase = (t < 3) ? n0 : m0;
#pragma unroll
            for (int it = 0; it < 2; ++it) {
                int idx = tid + it * 256;
                int row = idx >> 2, c = idx & 3;
                int4 v = *reinterpret_cast<const int4*>(
                    &src[(bN + rbase + row) * (size_t)D_ + k0 + c * 8]);
                *reinterpret_cast<int4*>(&tiles[t][row][c * 8]) = v;
            }
        }
        __syncthreads();

        const int rr = lane & 15, ko = (lane >> 4) * 8;
        short8v aF[3][4];
#pragma unroll
        for (int p = 0; p < 3; ++p)
#pragma unroll
            for (int mi = 0; mi < 4; ++mi)
                aF[p][mi] = *reinterpret_cast<const short8v*>(
                    &tiles[p][wr * 64 + mi * 16 + rr][ko]);
#pragma unroll
        for (int q = 0; q < 3; ++q) {
            short8v bF[4];
#pragma unroll
            for (int ni = 0; ni < 4; ++ni)
                bF[ni] = *reinterpret_cast<const short8v*>(
                    &tiles[3 + q][wc * 64 + ni * 16 + rr][ko]);
#pragma unroll
            for (int p = 0; p < 3; ++p) {
                if (p + q > 2) continue;     // keep ah, al, am, bh, bl, ch
#pragma unroll
                for (int mi = 0; mi < 4; ++mi)
#pragma unroll
                    for (int ni = 0; ni < 4; ++ni)
                        acc[mi][ni] = __builtin_amdgcn_mfma_f32_16x16x32_bf16(
                            aF[p][mi], bF[ni], acc[mi][ni], 0, 0, 0);
            }
        }
        __syncthreads();
    }

    // ---- fold to per-row top-8 over this chunk: 4 passes of 32 rows ----
    const int r4 = (lane >> 4) * 4, cl = lane & 15;
#pragma unroll
    for (int p = 0; p < 4; ++p) {
        if (wr == (p >> 1)) {
#pragma unroll
            for (int mi2 = 0; mi2 < 2; ++mi2) {
                const int mi = (p & 1) * 2 + mi2;
#pragma unroll
                for (int r = 0; r < 4; ++r) {
                    int rowh = mi * 16 + r4 + r;        // 0..63 within wave half
                    int rloc = rowh - (p & 1) * 32;     // 0..31
                    int n = n0 + wr * 64 + rowh;
#pragma unroll
                    for (int ni = 0; ni < 4; ++ni) {
                        int col = wc * 64 + ni * 16 + cl;
                        int m = m0 + col;
                        bool ok = (m <= n);
                        MV[rloc * 128 + col] = ok ? (acc[mi][ni][r] * SCALE_ + ALPHA_ * Ps[col])
                                                  : -INFINITY;
                        MI[rloc * 128 + col] = ok ? m : 0x7fffffff;
                    }
                }
            }
        }
        __syncthreads();
        if (tid < 32) {
            float tv[KTOP]; int ti[KTOP];
#pragma unroll
            for (int j = 0; j < KTOP; ++j) { tv[j] = -INFINITY; ti[j] = 0x7fffffff; }
            for (int i2 = 0; i2 < 128; ++i2) {
                float s = MV[tid * 128 + i2];
                if (s == -INFINITY) continue;
                topk_insert(tv, ti, s, MI[tid * 128 + i2]);
            }
            int n = n0 + p * 32 + tid;
            size_t base = ((bN + n) * NCH + ch) * 8;
#pragma unroll
            for (int j = 0; j < KTOP; ++j) { WV[base + j] = tv[j]; WI[base + j] = ti[j]; }
        }
        __syncthreads();
    }
}

// ---------------------------------------------------------------------------
// attn_merge: merge <=16 chunk lists -> top-8 -> softmax -> gather bf16 V ->
// CCb (bf16, cols 1024..2047). Grid 2048 blocks, 4 rows each.
// ---------------------------------------------------------------------------
__global__ __launch_bounds__(256)
void attn_merge(const float* __restrict__ WV, const int* __restrict__ WI,
                const ushortT* __restrict__ V, ushortT* __restrict__ CCb)
{
    __shared__ float CV[4][128];
    __shared__ int   CI[4][128];
    __shared__ float Pp[4][KTOP];
    __shared__ int   Pi[4][KTOP];

    const int tid  = threadIdx.x;
    const int wv   = tid >> 6;
    const int lane = tid & 63;
    const int rid  = blockIdx.x * 4 + wv;
    const int b    = rid >> 11;
    const int n    = rid & (N_ - 1);
    const int ncand = ((n >> 7) + 1) * 8;
    const size_t cbase = (size_t)rid * (NCH * 8);

#pragma unroll
    for (int t = 0; t < 2; ++t) {
        int i = lane + t * 64;
        if (i < ncand) { CV[wv][i] = WV[cbase + i]; CI[wv][i] = WI[cbase + i]; }
        else           { CV[wv][i] = -INFINITY;     CI[wv][i] = 0x7fffffff;   }
    }
    __syncthreads();

    if (lane == 0) {
        float tv[KTOP]; int ti[KTOP];
#pragma unroll
        for (int j = 0; j < KTOP; ++j) { tv[j] = -INFINITY; ti[j] = 0x7fffffff; }
        for (int i = 0; i < 128; ++i) {
            float s = CV[wv][i];
            if (s == -INFINITY) continue;
            topk_insert(tv, ti, s, CI[wv][i]);
        }
        float mx = tv[0];
        float e[KTOP]; float sum = 0.f;
#pragma unroll
        for (int j = 0; j < KTOP; ++j) {
            e[j] = (tv[j] == -INFINITY) ? 0.f : __expf(tv[j] - mx);
            sum += e[j];
        }
        float inv = 1.f / sum;
#pragma unroll
        for (int j = 0; j < KTOP; ++j) {
            Pp[wv][j] = e[j] * inv;
            Pi[wv][j] = (tv[j] == -INFINITY) ? 0 : ti[j];
        }
    }
    __syncthreads();

    const size_t vbase = (size_t)b * N_ * D_;
#pragma unroll
    for (int it = 0; it < 2; ++it) {
        int c8 = (it * 64 + lane) * 8;       // 8 bf16 cols per lane per iter
        float o[8];
#pragma unroll
        for (int u = 0; u < 8; ++u) o[u] = 0.f;
#pragma unroll
        for (int j = 0; j < KTOP; ++j) {
            float p = Pp[wv][j];
            ushort4 v0 = *reinterpret_cast<const ushort4*>(
                &V[vbase + (size_t)Pi[wv][j] * D_ + c8]);
            ushort4 v1 = *reinterpret_cast<const ushort4*>(
                &V[vbase + (size_t)Pi[wv][j] * D_ + c8 + 4]);
            o[0] = fmaf(p, b2f(v0.x), o[0]); o[1] = fmaf(p, b2f(v0.y), o[1]);
            o[2] = fmaf(p, b2f(v0.z), o[2]); o[3] = fmaf(p, b2f(v0.w), o[3]);
            o[4] = fmaf(p, b2f(v1.x), o[4]); o[5] = fmaf(p, b2f(v1.y), o[5]);
            o[6] = fmaf(p, b2f(v1.z), o[6]); o[7] = fmaf(p, b2f(v1.w), o[7]);
        }
        ushort4 ob0 = {f2b(o[0]), f2b(o[1]), f2b(o[2]), f2b(o[3])};
        ushort4 ob1 = {f2b(o[4]), f2b(o[5]), f2b(o[6]), f2b(o[7])};
        *reinterpret_cast<ushort4*>(&CCb[(size_t)rid * 2048 + 1024 + c8]) = ob0;
        *reinterpret_cast<ushort4*>(&CCb[(size_t)rid * 2048 + 1024 + c8 + 4]) = ob1;
    }
}

// ---------------------------------------------------------------------------
extern "C" void kernel_launch(void* const* d_in, const int* in_sizes, int n_in,
                              void* d_out, int out_size, void* d_ws, size_t ws_size,
                              hipStream_t stream)
{
    const float* mu   = (const float*)d_in[0];
    const float* pher = (const float*)d_in[1];
    const float* Wq   = (const float*)d_in[2];
    const float* bq   = (const float*)d_in[3];
    const float* Wk   = (const float*)d_in[4];
    const float* bk   = (const float*)d_in[5];
    const float* Wv   = (const float*)d_in[6];
    const float* bv   = (const float*)d_in[7];
    const float* Wm1  = (const float*)d_in[8];
    const float* bm1  = (const float*)d_in[9];
    const float* Wm2  = (const float*)d_in[10];
    const float* bm2  = (const float*)d_in[11];
    const float* Wo   = (const float*)d_in[12];
    const float* bo   = (const float*)d_in[13];
    float* out = (float*)d_out;
    float* ws  = (float*)d_ws;

    const size_t SZ = (size_t)B_ * N_ * D_;     // 8388608
    const int M = B_ * N_;                      // 8192
    const size_t MEG = 1024 * 1024;

    // ---- workspace map (float units), overlapped by liveness ----
    ushortT* CCb  = (ushortT*)ws;                       // [8192][2048] bf16, live to end
    float*   AbF  = ws + SZ;                            // f32 pre-act; dead after silu
    float*   Nbuf = ws + 2 * SZ;                        // f32 pre-act; dead after silu
    ushortT* mu_b = (ushortT*)(ws + 3 * SZ);            // bf16 mu; dead after V gemm
    ushortT* Sb   = (ushortT*)(ws + 3 * SZ + SZ / 2);   // bf16 S; dead after local gemm
    ushortT* Wt_m1 = (ushortT*)(ws + 4 * SZ);           // [1024][2048]
    ushortT* Wt_m2 = Wt_m1 + 2 * MEG;                   // [1024][1024]
    ushortT* Wt_v  = Wt_m2 + MEG;                       // [1024][1024]
    ushortT* Vb16  = (ushortT*)(ws + 4 * SZ + 2 * MEG); // bf16 V [8192][1024] (SZ/2 floats)
    ushortT* Qc    = (ushortT*)(ws + 4 * SZ + 2 * MEG + SZ / 2);  // SZ/2 floats
    ushortT* Kc    = (ushortT*)(ws + 4 * SZ + 2 * MEG + SZ);      // SZ/2 floats
    // overlays (phase 2):
    ushortT* Qa  = (ushortT*)AbF;            // plane = SZ ushorts
    ushortT* Qb2 = Qa + SZ;
    ushortT* Ka  = (ushortT*)Nbuf;
    ushortT* Kb2 = Ka + SZ;
    float*   WVb = (float*)Sb;               // [M][16][8] f32 (1M floats)
    int*     WIb = (int*)(WVb + MEG);        // 1M ints
    ushortT* Wt_o = mu_b;                    // [2048 rows? no: [1024][2048] bf16]

    dim3 blk256(256);
    dim3 gD(8, 64);                 // 128x128 tiles over (1024 cols, 8192 rows)

    // ---- local path (bf16 MFMA) ----
    hipLaunchKernelGGL(f32_to_bf16_k, dim3(SZ / 8 / 256), blk256, 0, stream, mu, mu_b);
    hipLaunchKernelGGL(transpose_f2b, dim3(64, 32), blk256, 0, stream, Wm1, Wt_m1, 2048, 1024);
    hipLaunchKernelGGL(transpose_f2b, dim3(32, 32), blk256, 0, stream, Wm2, Wt_m2, 1024, 1024);
    hipLaunchKernelGGL((mfma_gemm<0>), gD, blk256, 0, stream,
                       mu_b, D_, Wt_m1, 2048, bm1, (void*)AbF, D_, D_);
    hipLaunchKernelGGL((mfma_gemm<0>), gD, blk256, 0, stream,
                       mu_b, D_, Wt_m1 + 1024, 2048, (const float*)nullptr, (void*)Nbuf, D_, D_);
    hipLaunchKernelGGL(silu_mean, dim3(SZ / 4 / 256), blk256, 0, stream, AbF, Nbuf, Sb);
    hipLaunchKernelGGL((mfma_gemm<1>), gD, blk256, 0, stream,
                       Sb, D_, Wt_m2, D_, bm2, (void*)CCb, 2 * D_, D_);

    // ---- V (bf16 MFMA, bf16 out) ----
    hipLaunchKernelGGL(transpose_f2b, dim3(32, 32), blk256, 0, stream, Wv, Wt_v, 1024, 1024);
    hipLaunchKernelGGL((mfma_gemm<1>), gD, blk256, 0, stream,
                       mu_b, D_, Wt_v, D_, bv, (void*)Vb16, D_, D_);
    // Wo transpose AFTER V gemm (Wt_o overlays mu_b)
    hipLaunchKernelGGL(transpose_f2b, dim3(64, 32), blk256, 0, stream, Wo, Wt_o, 2048, 1024);

    // ---- Q/K projections: f32-exact GEMM + 3-way bf16 split epilogue ----
    // (planes overlay AbF/Nbuf, which are dead after silu_mean)
    hipLaunchKernelGGL(gemm_bias_split3, gD, blk256, 0, stream,
                       mu, Wq, bq, Qa, Qb2, Qc, D_, D_);
    hipLaunchKernelGGL(gemm_bias_split3, gD, blk256, 0, stream,
                       mu, Wk, bk, Ka, Kb2, Kc, D_, D_);

    // ---- scores: 6-product split MFMA + per-chunk top-8 ----
    hipLaunchKernelGGL(attn_scores_mfma, dim3(136, B_), blk256, 0, stream,
                       Qa, Qb2, Qc, Ka, Kb2, Kc, pher, WVb, WIb);

    // ---- merge + softmax + V gather -> CCb[:, D:2D] ----
    hipLaunchKernelGGL(attn_merge, dim3(M / 4), blk256, 0, stream, WVb, WIb, Vb16, CCb);

    // ---- out = CCb @ Wo + bo (bf16 MFMA, K=2048) ----
    hipLaunchKernelGGL((mfma_gemm<0>), gD, blk256, 0, stream,
                       CCb, 2 * D_, Wt_o, 2048, bo, (void*)out, D_, 2 * D_);

    (void)in_sizes; (void)n_in; (void)out_size; (void)ws_size;
}

// Round 7
// 896.102 us; speedup vs baseline: 3.7258x; 1.6255x over previous
//
#include <hip/hip_runtime.h>
#include <hip/hip_bf16.h>
#include <math.h>

#define B_ 4
#define N_ 2048
#define D_ 1024
#define WIN_ 4
#define KTOP 8
#define ALPHA_ 0.3f
#define SCALE_ (1.0f/32.0f)
#define NCH 16          // N_/128 col chunks
#define TROW 36         // ushorts per LDS tile row (72B stride)

typedef unsigned short ushortT;
typedef __attribute__((ext_vector_type(8))) short short8v;   // 8 bf16 (4 VGPR)
typedef __attribute__((ext_vector_type(4))) float f32x4;

__device__ inline ushortT f2b(float f) {     // f32 -> bf16 RNE
    unsigned int u = __float_as_uint(f);
    unsigned int r = (u + 0x7fffu + ((u >> 16) & 1u)) >> 16;
    return (ushortT)r;
}
__device__ inline float b2f(ushortT u) {
    return __uint_as_float(((unsigned int)u) << 16);
}

// ---------------------------------------------------------------------------
// mu f32 -> 3 bf16 planes: a contiguous, b contiguous, c STRIDED into CCb's
// right half (row*2048 + 1024 + col).
// ---------------------------------------------------------------------------
__global__ __launch_bounds__(256)
void split3_mu(const float* __restrict__ src, ushortT* __restrict__ Pa,
               ushortT* __restrict__ Pb, ushortT* __restrict__ CCbase)
{
    size_t base = ((size_t)blockIdx.x * 256 + threadIdx.x) * 4;
    int row = (int)(base >> 10);
    int col = (int)(base & 1023);
    float4 v = *reinterpret_cast<const float4*>(&src[base]);
    ushort4 pa, pb, pc;
    float vv[4] = {v.x, v.y, v.z, v.w};
#pragma unroll
    for (int j = 0; j < 4; ++j) {
        float f = vv[j];
        ushortT a = f2b(f);  float r1 = f - b2f(a);
        ushortT b = f2b(r1); float r2 = r1 - b2f(b);
        ushortT c = f2b(r2);
        ((ushortT*)&pa)[j] = a; ((ushortT*)&pb)[j] = b; ((ushortT*)&pc)[j] = c;
    }
    *reinterpret_cast<ushort4*>(&Pa[base]) = pa;
    *reinterpret_cast<ushort4*>(&Pb[base]) = pb;
    *reinterpret_cast<ushort4*>(&CCbase[(size_t)row * 2048 + 1024 + col]) = pc;
}

// ---------------------------------------------------------------------------
// W [K][Nn] f32 -> Wt [Nn][K] bf16 (single plane)
// ---------------------------------------------------------------------------
__global__ __launch_bounds__(256)
void transpose_f2b(const float* __restrict__ W, ushortT* __restrict__ Wt,
                   int K, int Nn)
{
    __shared__ float t[32][33];
    const int k0 = blockIdx.x * 32, n0 = blockIdx.y * 32;
    const int tx = threadIdx.x & 31, ty8 = threadIdx.x >> 5;
#pragma unroll
    for (int p = 0; p < 4; ++p) {
        int kk = p * 8 + ty8;
        t[kk][tx] = W[(size_t)(k0 + kk) * Nn + n0 + tx];
    }
    __syncthreads();
#pragma unroll
    for (int p = 0; p < 4; ++p) {
        int nn = p * 8 + ty8;
        Wt[(size_t)(n0 + nn) * K + k0 + tx] = f2b(t[tx][nn]);
    }
}

// ---------------------------------------------------------------------------
// W [K][Nn] f32 -> 3 transposed bf16 planes [Nn][K]
// ---------------------------------------------------------------------------
__global__ __launch_bounds__(256)
void transpose_split3(const float* __restrict__ W, ushortT* __restrict__ Pa,
                      ushortT* __restrict__ Pb, ushortT* __restrict__ Pc,
                      int K, int Nn)
{
    __shared__ float t[32][33];
    const int k0 = blockIdx.x * 32, n0 = blockIdx.y * 32;
    const int tx = threadIdx.x & 31, ty8 = threadIdx.x >> 5;
#pragma unroll
    for (int p = 0; p < 4; ++p) {
        int kk = p * 8 + ty8;
        t[kk][tx] = W[(size_t)(k0 + kk) * Nn + n0 + tx];
    }
    __syncthreads();
#pragma unroll
    for (int p = 0; p < 4; ++p) {
        int nn = p * 8 + ty8;
        float f = t[tx][nn];
        ushortT a = f2b(f);  float r1 = f - b2f(a);
        ushortT b = f2b(r1); float r2 = r1 - b2f(b);
        ushortT c = f2b(r2);
        size_t o = (size_t)(n0 + nn) * K + k0 + tx;
        Pa[o] = a; Pb[o] = b; Pc[o] = c;
    }
}

// ---------------------------------------------------------------------------
// bf16 MFMA GEMM (proven): 128x128 tile, BK=64, 4 waves, 64x64/wave.
// ---------------------------------------------------------------------------
template<int BF16OUT>
__global__ __launch_bounds__(256)
void mfma_gemm(const ushortT* __restrict__ A, int lda,
               const ushortT* __restrict__ Bt, int ldb,
               const float* __restrict__ bias,
               void* __restrict__ Cout, int ldc, int K)
{
    __shared__ ushortT AsL[128 * 72];
    __shared__ ushortT BsL[128 * 72];
    const int tid = threadIdx.x;
    const int m0 = blockIdx.y * 128;
    const int n0 = blockIdx.x * 128;
    const int w = tid >> 6, lane = tid & 63;
    const int wr = w >> 1, wc = w & 1;

    f32x4 acc[4][4];
#pragma unroll
    for (int mi = 0; mi < 4; ++mi)
#pragma unroll
        for (int ni = 0; ni < 4; ++ni) acc[mi][ni] = (f32x4){0.f, 0.f, 0.f, 0.f};

    for (int k0 = 0; k0 < K; k0 += 64) {
#pragma unroll
        for (int it = 0; it < 4; ++it) {
            int idx = tid + it * 256;        // 0..1023
            int row = idx >> 3, c = idx & 7;
            int4 va = *reinterpret_cast<const int4*>(&A[(size_t)(m0 + row) * lda + k0 + c * 8]);
            *reinterpret_cast<int4*>(&AsL[row * 72 + c * 8]) = va;
            int4 vb = *reinterpret_cast<const int4*>(&Bt[(size_t)(n0 + row) * ldb + k0 + c * 8]);
            *reinterpret_cast<int4*>(&BsL[row * 72 + c * 8]) = vb;
        }
        __syncthreads();
#pragma unroll
        for (int kh = 0; kh < 2; ++kh) {
            const int ko = kh * 32 + (lane >> 4) * 8;
            const int rr = lane & 15;
            short8v af[4], bf[4];
#pragma unroll
            for (int mi = 0; mi < 4; ++mi)
                af[mi] = *reinterpret_cast<const short8v*>(&AsL[(wr * 64 + mi * 16 + rr) * 72 + ko]);
#pragma unroll
            for (int ni = 0; ni < 4; ++ni)
                bf[ni] = *reinterpret_cast<const short8v*>(&BsL[(wc * 64 + ni * 16 + rr) * 72 + ko]);
#pragma unroll
            for (int mi = 0; mi < 4; ++mi)
#pragma unroll
                for (int ni = 0; ni < 4; ++ni)
                    acc[mi][ni] = __builtin_amdgcn_mfma_f32_16x16x32_bf16(
                        af[mi], bf[ni], acc[mi][ni], 0, 0, 0);
        }
        __syncthreads();
    }

    const int r4 = (lane >> 4) * 4, cl = lane & 15;
#pragma unroll
    for (int mi = 0; mi < 4; ++mi)
#pragma unroll
        for (int ni = 0; ni < 4; ++ni) {
            int row = m0 + wr * 64 + mi * 16 + r4;
            int col = n0 + wc * 64 + ni * 16 + cl;
            float bb = bias ? bias[col] : 0.f;
#pragma unroll
            for (int r = 0; r < 4; ++r) {
                float v = acc[mi][ni][r] + bb;
                if (BF16OUT)
                    ((ushortT*)Cout)[(size_t)(row + r) * ldc + col] = f2b(v);
                else
                    ((float*)Cout)[(size_t)(row + r) * ldc + col] = v;
            }
        }
}

// ---------------------------------------------------------------------------
// S[b,n,:] = mean_w silu(A + Nb shifted), output bf16.
// ---------------------------------------------------------------------------
__global__ __launch_bounds__(256)
void silu_mean(const float* __restrict__ A, const float* __restrict__ Nb,
               ushortT* __restrict__ Sb)
{
    size_t idx4 = (size_t)blockIdx.x * blockDim.x + threadIdx.x;
    size_t base = idx4 << 2;
    int n = (int)((base >> 10) & (N_ - 1));
    float4 a = *reinterpret_cast<const float4*>(&A[base]);
    float sx = 0.f, sy = 0.f, sz = 0.f, sw = 0.f;
#pragma unroll
    for (int w = 1; w <= WIN_; ++w) {
        float xx = a.x, xy = a.y, xz = a.z, xw = a.w;
        if (n >= w) {
            const float4 nb = *reinterpret_cast<const float4*>(&Nb[base - (size_t)w * D_]);
            xx += nb.x; xy += nb.y; xz += nb.z; xw += nb.w;
        }
        sx += xx / (1.f + __expf(-xx));
        sy += xy / (1.f + __expf(-xy));
        sz += xz / (1.f + __expf(-xz));
        sw += xw / (1.f + __expf(-xw));
    }
    ushort4 o = {f2b(sx * 0.25f), f2b(sy * 0.25f), f2b(sz * 0.25f), f2b(sw * 0.25f)};
    *reinterpret_cast<ushort4*>(&Sb[base]) = o;
}

// ---------------------------------------------------------------------------
__device__ inline void topk_insert(float (&tv)[KTOP], int (&ti)[KTOP], float s, int m)
{
    if ((s > tv[KTOP-1]) || (s == tv[KTOP-1] && m < ti[KTOP-1])) {
        float cs = s; int ci = m;
#pragma unroll
        for (int q = 0; q < KTOP; ++q) {
            bool beats = (cs > tv[q]) || (cs == tv[q] && ci < ti[q]);
            if (beats) { float t0 = tv[q]; int t1 = ti[q];
                         tv[q] = cs; ti[q] = ci; cs = t0; ci = t1; }
        }
    }
}

// ---------------------------------------------------------------------------
// Shared 6-product split-MFMA core macro pieces (p+q<=2: ah, al, am, bh, bl, ch)
// wave tile 64x32: wr in {0,1}, wc in {0..3}; acc[4][2].
// ---------------------------------------------------------------------------
#define SPLIT6_COMPUTE(T6, wr, wc, lane, acc)                                   \
    {                                                                           \
        const int rr_ = (lane) & 15, ko_ = ((lane) >> 4) * 8;                   \
        _Pragma("unroll")                                                       \
        for (int p_ = 0; p_ < 3; ++p_) {                                        \
            short8v aF_[4];                                                     \
            _Pragma("unroll")                                                   \
            for (int mi_ = 0; mi_ < 4; ++mi_)                                   \
                aF_[mi_] = *reinterpret_cast<const short8v*>(                   \
                    &T6[p_ * 4608 + ((wr) * 64 + mi_ * 16 + rr_) * TROW + ko_]);\
            _Pragma("unroll")                                                   \
            for (int q_ = 0; q_ < 3; ++q_) {                                    \
                if (p_ + q_ > 2) continue;                                      \
                short8v b0_ = *reinterpret_cast<const short8v*>(                \
                    &T6[(3 + q_) * 4608 + ((wc) * 32 + rr_) * TROW + ko_]);     \
                short8v b1_ = *reinterpret_cast<const short8v*>(                \
                    &T6[(3 + q_) * 4608 + ((wc) * 32 + 16 + rr_) * TROW + ko_]);\
                _Pragma("unroll")                                               \
                for (int mi_ = 0; mi_ < 4; ++mi_) {                             \
                    acc[mi_][0] = __builtin_amdgcn_mfma_f32_16x16x32_bf16(      \
                        aF_[mi_], b0_, acc[mi_][0], 0, 0, 0);                   \
                    acc[mi_][1] = __builtin_amdgcn_mfma_f32_16x16x32_bf16(      \
                        aF_[mi_], b1_, acc[mi_][1], 0, 0, 0);                   \
                }                                                               \
            }                                                                   \
        }                                                                       \
    }

// ---------------------------------------------------------------------------
// gemm_split6: out = (A0+A1+A2) @ (B0+B1+B2)^T + bias with 6 kept products,
// f32-equivalent. A-planes: lda0 (A0,A1 share), ldac for A2 (strided plane).
// Output split into 3 bf16 planes (ldc = D_). 512 thr, 8 waves, BK=32,
// reg-prefetch pipeline, XCD-chunked swizzle (grid 8x64 = 512 blocks).
// ---------------------------------------------------------------------------
__global__ __launch_bounds__(512, 4)
void gemm_split6(const ushortT* __restrict__ A0, const ushortT* __restrict__ A1,
                 const ushortT* __restrict__ A2, int lda, int ldac,
                 const ushortT* __restrict__ B0, const ushortT* __restrict__ B1,
                 const ushortT* __restrict__ B2,
                 const float* __restrict__ bias,
                 ushortT* __restrict__ Pa, ushortT* __restrict__ Pb,
                 ushortT* __restrict__ Pc)
{
    __shared__ ushortT T6[6 * 128 * TROW];     // 55296 B

    int lin = blockIdx.y * 8 + blockIdx.x;                // 0..511
    lin = (lin & 7) * 64 + (lin >> 3);                    // XCD-chunked
    const int m0 = (lin >> 3) * 128;
    const int n0 = (lin & 7) * 128;

    const int tid = threadIdx.x;
    const int wid = tid >> 6, lane = tid & 63;
    const int wr = wid >> 2, wc = wid & 3;
    const int rowL = tid >> 2, cL = tid & 3;              // stage: row 0..127, 16B chunk

    const size_t offA  = (size_t)(m0 + rowL) * lda + cL * 8;
    const size_t offAc = (size_t)(m0 + rowL) * ldac + cL * 8;
    const size_t offB  = (size_t)(n0 + rowL) * D_ + cL * 8;
    const int ldst = rowL * TROW + cL * 8;                // ushort offset in tile

    f32x4 acc[4][2];
#pragma unroll
    for (int mi = 0; mi < 4; ++mi) { acc[mi][0] = (f32x4){0,0,0,0}; acc[mi][1] = (f32x4){0,0,0,0}; }

    int4 s0, s1, s2, s3, s4, s5;
    s0 = *reinterpret_cast<const int4*>(&A0[offA]);
    s1 = *reinterpret_cast<const int4*>(&A1[offA]);
    s2 = *reinterpret_cast<const int4*>(&A2[offAc]);
    s3 = *reinterpret_cast<const int4*>(&B0[offB]);
    s4 = *reinterpret_cast<const int4*>(&B1[offB]);
    s5 = *reinterpret_cast<const int4*>(&B2[offB]);

    for (int ks = 0; ks < 32; ++ks) {
        __syncthreads();
        *reinterpret_cast<int4*>(&T6[0 * 4608 + ldst]) = s0;
        *reinterpret_cast<int4*>(&T6[1 * 4608 + ldst]) = s1;
        *reinterpret_cast<int4*>(&T6[2 * 4608 + ldst]) = s2;
        *reinterpret_cast<int4*>(&T6[3 * 4608 + ldst]) = s3;
        *reinterpret_cast<int4*>(&T6[4 * 4608 + ldst]) = s4;
        *reinterpret_cast<int4*>(&T6[5 * 4608 + ldst]) = s5;
        __syncthreads();
        if (ks < 31) {
            const int kk = (ks + 1) * 32;
            s0 = *reinterpret_cast<const int4*>(&A0[offA + kk]);
            s1 = *reinterpret_cast<const int4*>(&A1[offA + kk]);
            s2 = *reinterpret_cast<const int4*>(&A2[offAc + kk]);
            s3 = *reinterpret_cast<const int4*>(&B0[offB + kk]);
            s4 = *reinterpret_cast<const int4*>(&B1[offB + kk]);
            s5 = *reinterpret_cast<const int4*>(&B2[offB + kk]);
        }
        SPLIT6_COMPUTE(T6, wr, wc, lane, acc)
    }

    const int r4 = (lane >> 4) * 4, cl = lane & 15;
#pragma unroll
    for (int mi = 0; mi < 4; ++mi)
#pragma unroll
        for (int ni = 0; ni < 2; ++ni) {
            int col = n0 + wc * 32 + ni * 16 + cl;
            float bb = bias[col];
#pragma unroll
            for (int r = 0; r < 4; ++r) {
                int row = m0 + wr * 64 + mi * 16 + r4 + r;
                float v = acc[mi][ni][r] + bb;
                ushortT a = f2b(v);  float r1 = v - b2f(a);
                ushortT b = f2b(r1); float r2 = r1 - b2f(b);
                ushortT c = f2b(r2);
                size_t o = (size_t)row * D_ + col;
                Pa[o] = a; Pb[o] = b; Pc[o] = c;
            }
        }
}

// ---------------------------------------------------------------------------
// attn_scores_mfma2: 6-product split scores + causal mask + pheromone +
// per-chunk top-8. 512 thr, 8 waves, BK=32, reg-prefetch, XCD swizzle over
// the full 544-block causal enumeration. Fold: 128-thread partial scan.
// ---------------------------------------------------------------------------
__global__ __launch_bounds__(512, 4)
void attn_scores_mfma2(const ushortT* __restrict__ Qa, const ushortT* __restrict__ Qb2,
                       const ushortT* __restrict__ Qc,
                       const ushortT* __restrict__ Ka, const ushortT* __restrict__ Kb2,
                       const ushortT* __restrict__ Kc,
                       const float* __restrict__ pher,
                       float* __restrict__ WV, int* __restrict__ WI)
{
    __shared__ ushortT T6[6 * 128 * TROW];     // 55296 B
    __shared__ float Ps[128];
    float* MV = reinterpret_cast<float*>(&T6[0]);                    // [32][128]
    int*   MI = reinterpret_cast<int*>((char*)&T6[0] + 16384);       // [32][128]
    float* PV = reinterpret_cast<float*>((char*)&T6[0] + 32768);     // [32][4][8]
    int*   PI = reinterpret_cast<int*>((char*)&T6[0] + 36864);       // [32][4][8]

    int lin = blockIdx.y * 136 + blockIdx.x;              // 0..543
    lin = (lin & 7) * 68 + (lin >> 3);                    // XCD-chunked, 544=8*68
    const int b = lin / 136;
    const int xy = lin - b * 136;
    int g = 0;
    while ((g + 1) * (g + 2) / 2 <= xy) ++g;
    const int ch = xy - g * (g + 1) / 2;
    const int n0 = g * 128;
    const int m0 = ch * 128;
    const size_t bN = (size_t)b * N_;

    const int tid = threadIdx.x;
    const int wid = tid >> 6, lane = tid & 63;
    const int wr = wid >> 2, wc = wid & 3;
    const int rowL = tid >> 2, cL = tid & 3;

    if (tid < 128) Ps[tid] = pher[bN + m0 + tid];

    const size_t offQ = (bN + n0 + rowL) * (size_t)D_ + cL * 8;
    const size_t offK = (bN + m0 + rowL) * (size_t)D_ + cL * 8;
    const int ldst = rowL * TROW + cL * 8;

    f32x4 acc[4][2];
#pragma unroll
    for (int mi = 0; mi < 4; ++mi) { acc[mi][0] = (f32x4){0,0,0,0}; acc[mi][1] = (f32x4){0,0,0,0}; }

    int4 s0, s1, s2, s3, s4, s5;
    s0 = *reinterpret_cast<const int4*>(&Qa[offQ]);
    s1 = *reinterpret_cast<const int4*>(&Qb2[offQ]);
    s2 = *reinterpret_cast<const int4*>(&Qc[offQ]);
    s3 = *reinterpret_cast<const int4*>(&Ka[offK]);
    s4 = *reinterpret_cast<const int4*>(&Kb2[offK]);
    s5 = *reinterpret_cast<const int4*>(&Kc[offK]);

    for (int ks = 0; ks < 32; ++ks) {
        __syncthreads();
        *reinterpret_cast<int4*>(&T6[0 * 4608 + ldst]) = s0;
        *reinterpret_cast<int4*>(&T6[1 * 4608 + ldst]) = s1;
        *reinterpret_cast<int4*>(&T6[2 * 4608 + ldst]) = s2;
        *reinterpret_cast<int4*>(&T6[3 * 4608 + ldst]) = s3;
        *reinterpret_cast<int4*>(&T6[4 * 4608 + ldst]) = s4;
        *reinterpret_cast<int4*>(&T6[5 * 4608 + ldst]) = s5;
        __syncthreads();
        if (ks < 31) {
            const int kk = (ks + 1) * 32;
            s0 = *reinterpret_cast<const int4*>(&Qa[offQ + kk]);
            s1 = *reinterpret_cast<const int4*>(&Qb2[offQ + kk]);
            s2 = *reinterpret_cast<const int4*>(&Qc[offQ + kk]);
            s3 = *reinterpret_cast<const int4*>(&Ka[offK + kk]);
            s4 = *reinterpret_cast<const int4*>(&Kb2[offK + kk]);
            s5 = *reinterpret_cast<const int4*>(&Kc[offK + kk]);
        }
        SPLIT6_COMPUTE(T6, wr, wc, lane, acc)
    }

    // ---- fold to per-row top-8: 4 passes of 32 rows ----
    const int r4 = (lane >> 4) * 4, cl = lane & 15;
    for (int p = 0; p < 4; ++p) {
        __syncthreads();                       // T6/MV consumers done
        if (wr == (p >> 1)) {
#pragma unroll
            for (int mi2 = 0; mi2 < 2; ++mi2) {
                const int mi = (p & 1) * 2 + mi2;
#pragma unroll
                for (int ni = 0; ni < 2; ++ni) {
                    int col = wc * 32 + ni * 16 + cl;
                    int m = m0 + col;
#pragma unroll
                    for (int r = 0; r < 4; ++r) {
                        int rloc = mi2 * 16 + r4 + r;
                        int n = n0 + p * 32 + rloc;
                        bool ok = (m <= n);
                        MV[rloc * 128 + col] = ok ? (acc[mi][ni][r] * SCALE_ + ALPHA_ * Ps[col])
                                                  : -INFINITY;
                        MI[rloc * 128 + col] = ok ? m : 0x7fffffff;
                    }
                }
            }
        }
        __syncthreads();
        if (tid < 128) {                       // partial top-8 over a 32-col quarter
            const int row = tid >> 2, q4 = tid & 3;
            float tv[KTOP]; int ti[KTOP];
#pragma unroll
            for (int j = 0; j < KTOP; ++j) { tv[j] = -INFINITY; ti[j] = 0x7fffffff; }
            for (int j = 0; j < 32; ++j) {
                float s = MV[row * 128 + q4 * 32 + j];
                if (s == -INFINITY) continue;
                topk_insert(tv, ti, s, MI[row * 128 + q4 * 32 + j]);
            }
#pragma unroll
            for (int j = 0; j < KTOP; ++j) {
                PV[(row * 4 + q4) * 8 + j] = tv[j];
                PI[(row * 4 + q4) * 8 + j] = ti[j];
            }
        }
        __syncthreads();
        if (tid < 32) {                        // merge 4 partials -> chunk top-8
            float tv[KTOP]; int ti[KTOP];
#pragma unroll
            for (int j = 0; j < KTOP; ++j) { tv[j] = -INFINITY; ti[j] = 0x7fffffff; }
            for (int i = 0; i < 32; ++i) {
                float s = PV[tid * 32 + i];
                if (s == -INFINITY) continue;
                topk_insert(tv, ti, s, PI[tid * 32 + i]);
            }
            int n = n0 + p * 32 + tid;
            size_t base = ((bN + n) * NCH + ch) * 8;
#pragma unroll
            for (int j = 0; j < KTOP; ++j) { WV[base + j] = tv[j]; WI[base + j] = ti[j]; }
        }
    }
}

// ---------------------------------------------------------------------------
// attn_merge: merge <=16 chunk lists -> top-8 -> softmax -> gather bf16 V ->
// CCb right half. Grid 2048 blocks, 4 rows each.
// ---------------------------------------------------------------------------
__global__ __launch_bounds__(256)
void attn_merge(const float* __restrict__ WV, const int* __restrict__ WI,
                const ushortT* __restrict__ V, ushortT* __restrict__ CCb)
{
    __shared__ float CV[4][128];
    __shared__ int   CI[4][128];
    __shared__ float Pp[4][KTOP];
    __shared__ int   Pi[4][KTOP];

    const int tid  = threadIdx.x;
    const int wv   = tid >> 6;
    const int lane = tid & 63;
    const int rid  = blockIdx.x * 4 + wv;
    const int b    = rid >> 11;
    const int n    = rid & (N_ - 1);
    const int ncand = ((n >> 7) + 1) * 8;
    const size_t cbase = (size_t)rid * (NCH * 8);

#pragma unroll
    for (int t = 0; t < 2; ++t) {
        int i = lane + t * 64;
        if (i < ncand) { CV[wv][i] = WV[cbase + i]; CI[wv][i] = WI[cbase + i]; }
        else           { CV[wv][i] = -INFINITY;     CI[wv][i] = 0x7fffffff;   }
    }
    __syncthreads();

    if (lane == 0) {
        float tv[KTOP]; int ti[KTOP];
#pragma unroll
        for (int j = 0; j < KTOP; ++j) { tv[j] = -INFINITY; ti[j] = 0x7fffffff; }
        for (int i = 0; i < 128; ++i) {
            float s = CV[wv][i];
            if (s == -INFINITY) continue;
            topk_insert(tv, ti, s, CI[wv][i]);
        }
        float mx = tv[0];
        float e[KTOP]; float sum = 0.f;
#pragma unroll
        for (int j = 0; j < KTOP; ++j) {
            e[j] = (tv[j] == -INFINITY) ? 0.f : __expf(tv[j] - mx);
            sum += e[j];
        }
        float inv = 1.f / sum;
#pragma unroll
        for (int j = 0; j < KTOP; ++j) {
            Pp[wv][j] = e[j] * inv;
            Pi[wv][j] = (tv[j] == -INFINITY) ? 0 : ti[j];
        }
    }
    __syncthreads();

    const size_t vbase = (size_t)b * N_ * D_;
#pragma unroll
    for (int it = 0; it < 2; ++it) {
        int c8 = (it * 64 + lane) * 8;
        float o[8];
#pragma unroll
        for (int u = 0; u < 8; ++u) o[u] = 0.f;
#pragma unroll
        for (int j = 0; j < KTOP; ++j) {
            float p = Pp[wv][j];
            ushort4 v0 = *reinterpret_cast<const ushort4*>(
                &V[vbase + (size_t)Pi[wv][j] * D_ + c8]);
            ushort4 v1 = *reinterpret_cast<const ushort4*>(
                &V[vbase + (size_t)Pi[wv][j] * D_ + c8 + 4]);
            o[0] = fmaf(p, b2f(v0.x), o[0]); o[1] = fmaf(p, b2f(v0.y), o[1]);
            o[2] = fmaf(p, b2f(v0.z), o[2]); o[3] = fmaf(p, b2f(v0.w), o[3]);
            o[4] = fmaf(p, b2f(v1.x), o[4]); o[5] = fmaf(p, b2f(v1.y), o[5]);
            o[6] = fmaf(p, b2f(v1.z), o[6]); o[7] = fmaf(p, b2f(v1.w), o[7]);
        }
        ushort4 ob0 = {f2b(o[0]), f2b(o[1]), f2b(o[2]), f2b(o[3])};
        ushort4 ob1 = {f2b(o[4]), f2b(o[5]), f2b(o[6]), f2b(o[7])};
        *reinterpret_cast<ushort4*>(&CCb[(size_t)rid * 2048 + 1024 + c8]) = ob0;
        *reinterpret_cast<ushort4*>(&CCb[(size_t)rid * 2048 + 1024 + c8 + 4]) = ob1;
    }
}

// ---------------------------------------------------------------------------
extern "C" void kernel_launch(void* const* d_in, const int* in_sizes, int n_in,
                              void* d_out, int out_size, void* d_ws, size_t ws_size,
                              hipStream_t stream)
{
    const float* mu   = (const float*)d_in[0];
    const float* pher = (const float*)d_in[1];
    const float* Wq   = (const float*)d_in[2];
    const float* bq   = (const float*)d_in[3];
    const float* Wk   = (const float*)d_in[4];
    const float* bk   = (const float*)d_in[5];
    const float* Wv   = (const float*)d_in[6];
    const float* bv   = (const float*)d_in[7];
    const float* Wm1  = (const float*)d_in[8];
    const float* bm1  = (const float*)d_in[9];
    const float* Wm2  = (const float*)d_in[10];
    const float* bm2  = (const float*)d_in[11];
    const float* Wo   = (const float*)d_in[12];
    const float* bo   = (const float*)d_in[13];
    float* out = (float*)d_out;
    float* ws  = (float*)d_ws;

    const size_t SZ  = (size_t)B_ * N_ * D_;    // 8388608 floats
    const size_t MEG = 1024 * 1024;             // floats
    const int M = B_ * N_;                      // 8192

    // ---- workspace map (float units), total 5.5*SZ + 3*MEG ≈ 197 MB ----
    ushortT* CCb   = (ushortT*)ws;                        // [8192][2048] bf16
    ushortT* mu_cp = CCb + 1024;                          // strided plane, lda 2048 (CCb right half)
    float*   AbF   = ws + SZ;                             // f32 pre-act (phase 1)
    ushortT* Qa    = (ushortT*)(ws + SZ);                 // overlay after silu
    ushortT* Qb2   = Qa + SZ;
    float*   NbF   = ws + 2 * SZ;
    ushortT* Ka    = (ushortT*)(ws + 2 * SZ);
    ushortT* Kb2   = Ka + SZ;
    ushortT* mu_a  = (ushortT*)(ws + 3 * SZ);             // SZ ushorts
    ushortT* mu_bp = (ushortT*)(ws + 3 * SZ + SZ / 2);    // SZ ushorts
    float*   WVb   = (float*)(ws + 3 * SZ + SZ / 2);      // overlay after projections
    int*     WIb   = (int*)(WVb + MEG);
    ushortT* U     = (ushortT*)(ws + 4 * SZ);             // weights region, 3*MEG floats
    ushortT* Wt_m1 = U;                                   // [1024][2048] = 2M ush
    ushortT* Wt_m2 = U + 2 * MEG;                         // [1024][1024]
    ushortT* Wt_v  = U + 3 * MEG;                         // [1024][1024]
    ushortT* WqT_a = U;            ushortT* WqT_b = U + MEG;     ushortT* WqT_c = U + 2 * MEG;
    ushortT* WkT_a = U + 3 * MEG;  ushortT* WkT_b = U + 4 * MEG; ushortT* WkT_c = U + 5 * MEG;
    ushortT* Wt_o  = U;                                   // [1024][2048], after Q proj
    ushortT* Vb16  = (ushortT*)(ws + 4 * SZ + 3 * MEG);   // SZ ushorts
    ushortT* SbB   = (ushortT*)(ws + 4 * SZ + 3 * MEG + SZ / 2);  // SZ ushorts (then Qc)
    ushortT* Qc    = SbB;
    ushortT* Kc    = (ushortT*)(ws + 4 * SZ + 3 * MEG + SZ);      // SZ ushorts

    dim3 blk256(256), blk512(512);
    dim3 gD(8, 64);

    // 1. mu -> 3 bf16 planes (c strided into CCb right half)
    hipLaunchKernelGGL(split3_mu, dim3(SZ / 4 / 256), blk256, 0, stream, mu, mu_a, mu_bp, CCb);
    // 2. weight transposes (phase A)
    hipLaunchKernelGGL(transpose_f2b, dim3(64, 32), blk256, 0, stream, Wm1, Wt_m1, 2048, 1024);
    hipLaunchKernelGGL(transpose_f2b, dim3(32, 32), blk256, 0, stream, Wm2, Wt_m2, 1024, 1024);
    hipLaunchKernelGGL(transpose_f2b, dim3(32, 32), blk256, 0, stream, Wv, Wt_v, 1024, 1024);
    // 3-4. local pre-acts
    hipLaunchKernelGGL((mfma_gemm<0>), gD, blk256, 0, stream,
                       mu_a, D_, Wt_m1, 2048, bm1, (void*)AbF, D_, D_);
    hipLaunchKernelGGL((mfma_gemm<0>), gD, blk256, 0, stream,
                       mu_a, D_, Wt_m1 + 1024, 2048, (const float*)nullptr, (void*)NbF, D_, D_);
    // 5. silu-mean -> Sb (bf16)
    hipLaunchKernelGGL(silu_mean, dim3(SZ / 4 / 256), blk256, 0, stream, AbF, NbF, SbB);
    // 6. local msgs -> CCb left half
    hipLaunchKernelGGL((mfma_gemm<1>), gD, blk256, 0, stream,
                       SbB, D_, Wt_m2, D_, bm2, (void*)CCb, 2 * D_, D_);
    // 7. V -> bf16
    hipLaunchKernelGGL((mfma_gemm<1>), gD, blk256, 0, stream,
                       mu_a, D_, Wt_v, D_, bv, (void*)Vb16, D_, D_);
    // 8. Wq/Wk -> transposed split planes (phase B overlay)
    hipLaunchKernelGGL(transpose_split3, dim3(32, 32), blk256, 0, stream,
                       Wq, WqT_a, WqT_b, WqT_c, 1024, 1024);
    hipLaunchKernelGGL(transpose_split3, dim3(32, 32), blk256, 0, stream,
                       Wk, WkT_a, WkT_b, WkT_c, 1024, 1024);
    // 9-10. Q/K projections (split-MFMA, f32-equivalent) -> split planes
    hipLaunchKernelGGL(gemm_split6, gD, blk512, 0, stream,
                       mu_a, mu_bp, mu_cp, D_, 2 * D_,
                       WqT_a, WqT_b, WqT_c, bq, Qa, Qb2, Qc);
    hipLaunchKernelGGL(gemm_split6, gD, blk512, 0, stream,
                       mu_a, mu_bp, mu_cp, D_, 2 * D_,
                       WkT_a, WkT_b, WkT_c, bk, Ka, Kb2, Kc);
    // 11. Wo transpose (overlays dead WqT_a/b)
    hipLaunchKernelGGL(transpose_f2b, dim3(64, 32), blk256, 0, stream, Wo, Wt_o, 2048, 1024);
    // 12. scores + per-chunk top-8
    hipLaunchKernelGGL(attn_scores_mfma2, dim3(136, B_), blk512, 0, stream,
                       Qa, Qb2, Qc, Ka, Kb2, Kc, pher, WVb, WIb);
    // 13. merge + softmax + V gather -> CCb right half
    hipLaunchKernelGGL(attn_merge, dim3(M / 4), blk256, 0, stream, WVb, WIb, Vb16, CCb);
    // 14. out = CCb @ Wo + bo
    hipLaunchKernelGGL((mfma_gemm<0>), gD, blk256, 0, stream,
                       CCb, 2 * D_, Wt_o, 2048, bo, (void*)out, D_, 2 * D_);

    (void)in_sizes; (void)n_in; (void)out_size; (void)ws_size;
}